// Round 7
// baseline (556.742 us; speedup 1.0000x reference)
//
#include <hip/hip_runtime.h>
#include <cstdint>

#define B_SZ 1024

// ---------------------------------------------------------------------------
// Threefry-2x32 (20 rounds), exactly as jax._src.prng.threefry2x32.
// ---------------------------------------------------------------------------
__host__ __device__ inline void tf2x32(uint32_t k0, uint32_t k1,
                                       uint32_t x0, uint32_t x1,
                                       uint32_t& o0, uint32_t& o1) {
  uint32_t ks2 = 0x1BD11BDAu ^ k0 ^ k1;
#define TF_RND(r) { x0 += x1; x1 = (x1 << (r)) | (x1 >> (32 - (r))); x1 ^= x0; }
  x0 += k0; x1 += k1;
  TF_RND(13) TF_RND(15) TF_RND(26) TF_RND(6)
  x0 += k1; x1 += ks2 + 1u;
  TF_RND(17) TF_RND(29) TF_RND(16) TF_RND(24)
  x0 += ks2; x1 += k0 + 2u;
  TF_RND(13) TF_RND(15) TF_RND(26) TF_RND(6)
  x0 += k0; x1 += k1 + 3u;
  TF_RND(17) TF_RND(29) TF_RND(16) TF_RND(24)
  x0 += k1; x1 += ks2 + 4u;
  TF_RND(13) TF_RND(15) TF_RND(26) TF_RND(6)
  x0 += ks2; x1 += k0 + 5u;
#undef TF_RND
  o0 = x0; o1 = x1;
}

// XLA ErfInv f32 expansion, identical coefficients.
__device__ inline float erfinv_f32(float x) {
  float w = -log1pf(-x * x);
  float p;
  if (w < 5.0f) {
    w -= 2.5f;
    p = 2.81022636e-08f;
    p = fmaf(p, w, 3.43273939e-07f);
    p = fmaf(p, w, -3.5233877e-06f);
    p = fmaf(p, w, -4.39150654e-06f);
    p = fmaf(p, w, 0.00021858087f);
    p = fmaf(p, w, -0.00125372503f);
    p = fmaf(p, w, -0.00417768164f);
    p = fmaf(p, w, 0.246640727f);
    p = fmaf(p, w, 1.50140941f);
  } else {
    w = sqrtf(w) - 3.0f;
    p = -0.000200214257f;
    p = fmaf(p, w, 0.000100950558f);
    p = fmaf(p, w, 0.00134934322f);
    p = fmaf(p, w, -0.00367342844f);
    p = fmaf(p, w, 0.00573950773f);
    p = fmaf(p, w, -0.0076224613f);
    p = fmaf(p, w, 0.00943887047f);
    p = fmaf(p, w, 1.00167406f);
    p = fmaf(p, w, 2.83297682f);
  }
  return p * x;
}

__device__ inline float jax_normal_pt(uint32_t k0, uint32_t k1, uint32_t e) {
  uint32_t o0, o1;
  tf2x32(k0, k1, 0u, e, o0, o1);
  uint32_t bits = o0 ^ o1;
  float f = __uint_as_float((bits >> 9) | 0x3f800000u) - 1.0f;
  const float LO = -0.99999994f;
  float u = fmaxf(LO, fmaf(f, 2.0f, LO));
  return 1.41421356f * erfinv_f32(u);
}

struct OodArgs {
  const float* x;
  const float* noise_w;
  const float* noise_b;
  const float* feat_w[5];
  const float* feat_b[5];
  const float* mu_w[5];
  const float* mu_b[5];
  const float* std_w[5];
  const float* std_b[5];
  float* mean_out[5];
  float* std_out[5];
  float* scores;
  uint32_t fk0[5], fk1[5];
};

// LDS carve offsets (floats).  s_std (10*C <= 5120 floats) aliases the
// s_xp/s_xi region (dead after phase 3).
#define OFF_XP   0      // 3*34*34 = 3468 (padded x)
#define OFF_XI   3468   // 3*34*34 = 3468 (padded noised slice)
#define OFF_STD  0      // 10*C (max 5120) -- aliases XP/XI
#define OFF_G    6936   // 2*10*27 = 540
#define OFF_RS   7476   // 20
#define OFF_PART 7496   // 50
#define OFF_NW   7546   // 81
#define OFF_NB   7627   // 3
#define OFF_IDX  7630   // 1 (int)
#define SMEM_FLOATS 7631

// ---------------------------------------------------------------------------
// One block per (b, stage I). 320 threads: 20 (wh,k) groups x 16 spatial subs.
// Phase 3 runs as three per-ci passes so the accumulator live set stays ~45
// VGPRs (the 27 g-slots are independent sums; per-ci split costs 0 extra
// LDS reads / FMAs, only 3x w reloads from L2).
// ---------------------------------------------------------------------------
template<int I, int C, int S, int STRIDE>
__device__ __forceinline__ void stage_body(const OodArgs& A_, float* smem) {
  constexpr int Wd = 32 / STRIDE;   // output width

  const int b = blockIdx.x;
  const int t = threadIdx.x;

  float* s_xp  = smem + OFF_XP;
  float* s_xi  = smem + OFF_XI;
  float* s_std = smem + OFF_STD;   // [10][C], aliases s_xp/s_xi
  float* s_g   = smem + OFF_G;     // [2][10][27]
  float* s_rs  = smem + OFF_RS;    // [2][10]
  float* s_pt  = smem + OFF_PART;  // [10][5]
  float* s_nw  = smem + OFF_NW;
  float* s_nb  = smem + OFF_NB;
  int*   s_idx = (int*)(smem + OFF_IDX);

  const float* feat_w = A_.feat_w[I];
  const float* feat_b = A_.feat_b[I];
  const uint32_t fk0 = A_.fk0[I], fk1 = A_.fk1[I];

  // ---- phase 1: zero both padded buffers, load x[b] interior, weights ----
  for (int p = t; p < 2 * 3468; p += 320) smem[p] = 0.0f;
  if (t < 81) s_nw[t] = A_.noise_w[81 * I + t];
  if (t < 3)  s_nb[t] = A_.noise_b[3 * I + t];
  __syncthreads();
  const float* xb = A_.x + (size_t)b * 3072;
  for (int p = t; p < 3072; p += 320) {
    int ci = p >> 10; int rr = p & 1023; int yy = rr >> 5; int xx = rr & 31;
    s_xp[ci * 1156 + (yy + 1) * 34 + (xx + 1)] = xb[p];
  }
  __syncthreads();

  // ---- phase 2: xi = x + conv3x3(x, noise_w); branch-free via padding ----
  #pragma unroll
  for (int co = 0; co < 3; ++co) {           // output channel
    float nwr[27];
    #pragma unroll
    for (int j = 0; j < 27; ++j) nwr[j] = s_nw[co * 27 + j];  // broadcast
    const float nb = s_nb[co];
    for (int p = t; p < 1024; p += 320) {
      const int base = (p >> 5) * 34 + (p & 31);   // top-left in padded coords
      float a = nb;
      #pragma unroll
      for (int c2 = 0; c2 < 3; ++c2) {
        #pragma unroll
        for (int q = 0; q < 9; ++q)
          a = fmaf(s_xp[c2 * 1156 + base + (q / 3) * 34 + (q % 3)],
                   nwr[c2 * 9 + q], a);
      }
      s_xi[co * 1156 + base + 35] = a + s_xp[co * 1156 + base + 35];
    }
  }
  __syncthreads();

  // ---- phase 3: g[wh][k][ci*9+q] = sum_s w[k,s]*xi[ci,patch(s,q)] ----
  const int G  = t >> 4;          // 0..19
  const int ss = t & 15;          // spatial sub
  const int wh = G & 1;
  const int kk = G >> 1;
  const float* wsrc = (wh ? A_.std_w[I] : A_.mu_w[I]) + kk * S;

  if constexpr (STRIDE == 1) {
    // thread ss owns output rows 2ss, 2ss+1; one ci per pass (low pressure).
    const float* wr0 = wsrc + (2 * ss) * 32;
    const float* wr1 = wr0 + 32;
    const int rbase0 = (2 * ss) * 34;
    #pragma unroll
    for (int ci = 0; ci < 3; ++ci) {
      const int rb = ci * 1156 + rbase0;
      float acc[10];
      #pragma unroll
      for (int j = 0; j < 10; ++j) acc[j] = 0.0f;
      float Av[4], Bv[4], Cv[4];
      float4 w04, w14;
      #pragma unroll
      for (int u = 0; u < 4; ++u) {
        Av[u] = s_xi[rb + u * 34 + 0];
        Bv[u] = s_xi[rb + u * 34 + 1];
      }
#define WCOMP(V, L) ((L) == 0 ? (V).x : (L) == 1 ? (V).y : (L) == 2 ? (V).z : (V).w)
#define LDW(c) { w04 = *(const float4*)(wr0 + (c)); w14 = *(const float4*)(wr1 + (c)); }
#define STEP(c, P, Q, R) { \
    _Pragma("unroll") \
    for (int u = 0; u < 4; ++u) R[u] = s_xi[rb + u * 34 + (c) + 2]; \
    const float w0c = WCOMP(w04, (c) & 3); \
    const float w1c = WCOMP(w14, (c) & 3); \
    _Pragma("unroll") \
    for (int dy = 0; dy < 3; ++dy) { \
      acc[dy*3+0] = fmaf(w0c, P[dy], fmaf(w1c, P[dy+1], acc[dy*3+0])); \
      acc[dy*3+1] = fmaf(w0c, Q[dy], fmaf(w1c, Q[dy+1], acc[dy*3+1])); \
      acc[dy*3+2] = fmaf(w0c, R[dy], fmaf(w1c, R[dy+1], acc[dy*3+2])); \
    } \
    if (ci == 0) acc[9] += w0c + w1c; \
  }
#define G4_0(c) LDW(c) STEP(c, Av, Bv, Cv) STEP((c)+1, Bv, Cv, Av) STEP((c)+2, Cv, Av, Bv) STEP((c)+3, Av, Bv, Cv)
#define G4_1(c) LDW(c) STEP(c, Bv, Cv, Av) STEP((c)+1, Cv, Av, Bv) STEP((c)+2, Av, Bv, Cv) STEP((c)+3, Bv, Cv, Av)
#define G4_2(c) LDW(c) STEP(c, Cv, Av, Bv) STEP((c)+1, Av, Bv, Cv) STEP((c)+2, Bv, Cv, Av) STEP((c)+3, Cv, Av, Bv)

      G4_0(0) G4_1(4) G4_2(8) G4_0(12) G4_1(16) G4_2(20) G4_0(24) G4_1(28)

#undef G4_0
#undef G4_1
#undef G4_2
#undef STEP
#undef LDW
#undef WCOMP
      // reduce across the 16 spatial subs and retire this ci's accumulators
      const int nred = (ci == 0) ? 10 : 9;
      #pragma unroll
      for (int j = 0; j < 10; ++j) {
        if (j >= nred) break;
        float v = acc[j];
        v += __shfl_xor(v, 1, 64);
        v += __shfl_xor(v, 2, 64);
        v += __shfl_xor(v, 4, 64);
        v += __shfl_xor(v, 8, 64);
        acc[j] = v;
      }
      if (ss == 0) {
        #pragma unroll
        for (int j = 0; j < 9; ++j) s_g[(wh * 10 + kk) * 27 + ci * 9 + j] = acc[j];
        if (ci == 0) s_rs[wh * 10 + kk] = acc[9];
      }
    }
  } else {
    constexpr int PER = S / 16;          // 16 / 4 / 1
    #pragma unroll
    for (int ci = 0; ci < 3; ++ci) {
      float acc[10];
      #pragma unroll
      for (int j = 0; j < 10; ++j) acc[j] = 0.0f;
      #pragma unroll
      for (int u = 0; u < PER; ++u) {
        const int s  = ss * PER + u;
        const int yo = s / Wd, xo = s % Wd;
        const float wx = wsrc[s];
        #pragma unroll
        for (int dy = 0; dy < 3; ++dy) {
          const int base = ci * 1156 + (yo * STRIDE + dy + 1) * 34 + (xo * STRIDE + 1);
          #pragma unroll
          for (int dx = 0; dx < 3; ++dx)
            acc[dy * 3 + dx] = fmaf(wx, s_xi[base + dx], acc[dy * 3 + dx]);
        }
        if (ci == 0) acc[9] += wx;
      }
      const int nred = (ci == 0) ? 10 : 9;
      #pragma unroll
      for (int j = 0; j < 10; ++j) {
        if (j >= nred) break;
        float v = acc[j];
        v += __shfl_xor(v, 1, 64);
        v += __shfl_xor(v, 2, 64);
        v += __shfl_xor(v, 4, 64);
        v += __shfl_xor(v, 8, 64);
        acc[j] = v;
      }
      if (ss == 0) {
        #pragma unroll
        for (int j = 0; j < 9; ++j) s_g[(wh * 10 + kk) * 27 + ci * 9 + j] = acc[j];
        if (ci == 0) s_rs[wh * 10 + kk] = acc[9];
      }
    }
  }
  __syncthreads();

  // ---- phase 4a: s_std[k*C+c] for all classes (low pressure) ----
  for (int v = t; v < 10 * C; v += 320) {
    const int k2 = v / C; const int c = v - k2 * C;
    const float* fw = feat_w + c * 27;
    float a2 = 0.0f;
    #pragma unroll
    for (int j = 0; j < 27; ++j) a2 = fmaf(s_g[(10 + k2) * 27 + j], fw[j], a2);
    a2 = fmaf(feat_b[c], s_rs[10 + k2], a2) + A_.std_b[I][k2];
    s_std[v] = a2;
  }
  __syncthreads();

  // ---- phase 4b: mahal[k] = -0.5 * sum_c var*eps^2 with jax-exact eps ----
  float macc[10];
  #pragma unroll
  for (int k2 = 0; k2 < 10; ++k2) macc[k2] = 0.0f;
  for (int c = t; c < C; c += 320) {
    #pragma unroll
    for (int k2 = 0; k2 < 10; ++k2) {
      const float sd  = s_std[k2 * C + c];
      const float eps = jax_normal_pt(fk0, fk1, (uint32_t)((b * 10 + k2) * C + c));
      macc[k2] = fmaf(sd * sd, eps * eps, macc[k2]);
    }
  }
  const int lane = t & 63, wvi = t >> 6;
  #pragma unroll
  for (int k2 = 0; k2 < 10; ++k2) {
    float v = macc[k2];
    #pragma unroll
    for (int off = 32; off > 0; off >>= 1) v += __shfl_down(v, off, 64);
    if (lane == 0) s_pt[k2 * 5 + wvi] = v;
  }
  __syncthreads();
  if (t == 0) {
    float best = -INFINITY; int bi = 0;
    #pragma unroll
    for (int k2 = 0; k2 < 10; ++k2) {
      float m = -0.5f * (s_pt[k2 * 5 + 0] + s_pt[k2 * 5 + 1] + s_pt[k2 * 5 + 2] +
                         s_pt[k2 * 5 + 3] + s_pt[k2 * 5 + 4]);
      if (m > best) { best = m; bi = k2; }
    }
    A_.scores[b * 5 + I] = best;
    *s_idx = bi;
  }
  __syncthreads();

  // ---- phase 5: outputs (mean recomputed for argmax class; std from LDS) --
  const int idx = *s_idx;
  for (int c = t; c < C; c += 320) {
    const float* fw = feat_w + c * 27;
    float a1 = 0.0f;
    #pragma unroll
    for (int j = 0; j < 27; ++j) a1 = fmaf(s_g[idx * 27 + j], fw[j], a1);
    a1 = fmaf(feat_b[c], s_rs[idx], a1) + A_.mu_b[I][idx];
    A_.mean_out[I][(size_t)b * C + c] = a1;
    A_.std_out[I][(size_t)b * C + c]  = s_std[idx * C + c];
  }
}

__global__ __launch_bounds__(320, 8)
void ood_all(OodArgs A_) {
  __shared__ float smem[SMEM_FLOATS];
  switch (blockIdx.y) {
    case 0: stage_body<0,  64, 1024, 1>(A_, smem); break;
    case 1: stage_body<1,  64, 1024, 1>(A_, smem); break;
    case 2: stage_body<2, 128,  256, 2>(A_, smem); break;
    case 3: stage_body<3, 256,   64, 4>(A_, smem); break;
    default: stage_body<4, 512,  16, 8>(A_, smem); break;
  }
}

__global__ void ood_clf(const float* __restrict__ scores,  // (B,5)
                        const float* __restrict__ clf_w,   // (1,5)
                        const float* __restrict__ clf_b,   // (1,)
                        float* __restrict__ out) {         // (B,)
  int b = blockIdx.x * blockDim.x + threadIdx.x;
  if (b < B_SZ) {
    float acc = clf_b[0];
    #pragma unroll
    for (int i = 0; i < 5; ++i) acc = fmaf(scores[b * 5 + i], clf_w[i], acc);
    out[b] = acc;
  }
}

extern "C" void kernel_launch(void* const* d_in, const int* in_sizes, int n_in,
                              void* d_out, int out_size, void* d_ws, size_t ws_size,
                              hipStream_t stream) {
  (void)in_sizes; (void)n_in; (void)out_size; (void)ws_size;
  const float* clf_w = (const float*)d_in[33];
  const float* clf_b = (const float*)d_in[34];
  float* out    = (float*)d_out;
  float* scores = (float*)d_ws;   // B*5 floats

  OodArgs A_;
  A_.x       = (const float*)d_in[0];
  A_.noise_w = (const float*)d_in[1];
  A_.noise_b = (const float*)d_in[2];
  const size_t NMEAN = 1048576;
  const size_t moff[5] = {1024, 66560, 132096, 263168, 525312};
  for (int i = 0; i < 5; ++i) {
    A_.feat_w[i]   = (const float*)d_in[3 + 6 * i];
    A_.feat_b[i]   = (const float*)d_in[4 + 6 * i];
    A_.mu_w[i]     = (const float*)d_in[5 + 6 * i];
    A_.mu_b[i]     = (const float*)d_in[6 + 6 * i];
    A_.std_w[i]    = (const float*)d_in[7 + 6 * i];
    A_.std_b[i]    = (const float*)d_in[8 + 6 * i];
    A_.mean_out[i] = out + moff[i];
    A_.std_out[i]  = out + moff[i] + NMEAN;
    tf2x32(0u, 42u, 0u, (uint32_t)i, A_.fk0[i], A_.fk1[i]);
  }
  A_.scores = scores;

  ood_all<<<dim3(B_SZ, 5), 320, 0, stream>>>(A_);
  ood_clf<<<(B_SZ + 255) / 256, 256, 0, stream>>>(scores, clf_w, clf_b, out);
}

// Round 8
// 412.542 us; speedup vs baseline: 1.3495x; 1.3495x over previous
//
#include <hip/hip_runtime.h>
#include <cstdint>

#define B_SZ 1024

// ---------------------------------------------------------------------------
// Threefry-2x32 (20 rounds), exactly as jax._src.prng.threefry2x32.
// ---------------------------------------------------------------------------
__host__ __device__ inline void tf2x32(uint32_t k0, uint32_t k1,
                                       uint32_t x0, uint32_t x1,
                                       uint32_t& o0, uint32_t& o1) {
  uint32_t ks2 = 0x1BD11BDAu ^ k0 ^ k1;
#define TF_RND(r) { x0 += x1; x1 = (x1 << (r)) | (x1 >> (32 - (r))); x1 ^= x0; }
  x0 += k0; x1 += k1;
  TF_RND(13) TF_RND(15) TF_RND(26) TF_RND(6)
  x0 += k1; x1 += ks2 + 1u;
  TF_RND(17) TF_RND(29) TF_RND(16) TF_RND(24)
  x0 += ks2; x1 += k0 + 2u;
  TF_RND(13) TF_RND(15) TF_RND(26) TF_RND(6)
  x0 += k0; x1 += k1 + 3u;
  TF_RND(17) TF_RND(29) TF_RND(16) TF_RND(24)
  x0 += k1; x1 += ks2 + 4u;
  TF_RND(13) TF_RND(15) TF_RND(26) TF_RND(6)
  x0 += ks2; x1 += k0 + 5u;
#undef TF_RND
  o0 = x0; o1 = x1;
}

// XLA ErfInv f32 expansion, identical coefficients.
__device__ inline float erfinv_f32(float x) {
  float w = -log1pf(-x * x);
  float p;
  if (w < 5.0f) {
    w -= 2.5f;
    p = 2.81022636e-08f;
    p = fmaf(p, w, 3.43273939e-07f);
    p = fmaf(p, w, -3.5233877e-06f);
    p = fmaf(p, w, -4.39150654e-06f);
    p = fmaf(p, w, 0.00021858087f);
    p = fmaf(p, w, -0.00125372503f);
    p = fmaf(p, w, -0.00417768164f);
    p = fmaf(p, w, 0.246640727f);
    p = fmaf(p, w, 1.50140941f);
  } else {
    w = sqrtf(w) - 3.0f;
    p = -0.000200214257f;
    p = fmaf(p, w, 0.000100950558f);
    p = fmaf(p, w, 0.00134934322f);
    p = fmaf(p, w, -0.00367342844f);
    p = fmaf(p, w, 0.00573950773f);
    p = fmaf(p, w, -0.0076224613f);
    p = fmaf(p, w, 0.00943887047f);
    p = fmaf(p, w, 1.00167406f);
    p = fmaf(p, w, 2.83297682f);
  }
  return p * x;
}

__device__ inline float jax_normal_pt(uint32_t k0, uint32_t k1, uint32_t e) {
  uint32_t o0, o1;
  tf2x32(k0, k1, 0u, e, o0, o1);
  uint32_t bits = o0 ^ o1;
  float f = __uint_as_float((bits >> 9) | 0x3f800000u) - 1.0f;
  const float LO = -0.99999994f;
  float u = fmaxf(LO, fmaf(f, 2.0f, LO));
  return 1.41421356f * erfinv_f32(u);
}

struct OodArgs {
  const float* x;
  const float* noise_w;
  const float* noise_b;
  const float* feat_w[5];
  const float* feat_b[5];
  const float* mu_w[5];
  const float* mu_b[5];
  const float* std_w[5];
  const float* std_b[5];
  float* mean_out[5];
  float* std_out[5];
  float* scores;
  uint32_t fk0[5], fk1[5];
};

// Padded image buffers: 34 rows x pitch 35 per channel (pitch 35 => phase-3
// lane banks are 6*ss mod 32 = 16 distinct banks, conflict-free).
#define PITCH 35
#define CHSZ  (34 * PITCH)   // 1190
#define XSZ   (3 * CHSZ)     // 3570

// LDS carve offsets (floats). s_std (10*C <= 5120) aliases XP/XI (dead
// after phase 3).
#define OFF_XP   0           // 3570
#define OFF_XI   3570        // 3570
#define OFF_STD  0           // aliases
#define OFF_G    7140        // 540
#define OFF_RS   7680        // 20
#define OFF_PT   7700        // 10
#define OFF_NW   7710        // 81
#define OFF_NB   7791        // 3
#define OFF_IDX  7794        // 1 (int)
#define SMEM_FLOATS 7795

// ---------------------------------------------------------------------------
// One block per (b, stage I). 320 threads: 20 (wh,k) groups x 16 row-pairs.
// ---------------------------------------------------------------------------
template<int I, int C, int S, int STRIDE>
__device__ __forceinline__ void stage_body(const OodArgs& A_, float* smem) {
  constexpr int Wd = 32 / STRIDE;   // output width

  const int b = blockIdx.x;
  const int t = threadIdx.x;

  float* s_xp  = smem + OFF_XP;
  float* s_xi  = smem + OFF_XI;
  float* s_std = smem + OFF_STD;
  float* s_g   = smem + OFF_G;     // [2][10][27]
  float* s_rs  = smem + OFF_RS;    // [2][10]
  float* s_pt  = smem + OFF_PT;    // [10]
  float* s_nw  = smem + OFF_NW;
  float* s_nb  = smem + OFF_NB;
  int*   s_idx = (int*)(smem + OFF_IDX);

  const float* feat_w = A_.feat_w[I];
  const float* feat_b = A_.feat_b[I];
  const uint32_t fk0 = A_.fk0[I], fk1 = A_.fk1[I];

  // ---- phase 1: zero padded buffers, load x[b] interior, weights ----
  for (int p = t; p < 2 * XSZ; p += 320) smem[p] = 0.0f;
  if (t < 81) s_nw[t] = A_.noise_w[81 * I + t];
  if (t < 3)  s_nb[t] = A_.noise_b[3 * I + t];
  __syncthreads();
  const float* xb = A_.x + (size_t)b * 3072;
  for (int p = t; p < 3072; p += 320) {
    int ci = p >> 10; int rr = p & 1023; int yy = rr >> 5; int xx = rr & 31;
    s_xp[ci * CHSZ + (yy + 1) * PITCH + (xx + 1)] = xb[p];
  }
  __syncthreads();

  // ---- phase 2: xi = x + conv3x3(x, noise_w); branch-free via padding ----
  #pragma unroll
  for (int co = 0; co < 3; ++co) {
    float nwr[27];
    #pragma unroll
    for (int j = 0; j < 27; ++j) nwr[j] = s_nw[co * 27 + j];
    const float nb = s_nb[co];
    for (int p = t; p < 1024; p += 320) {
      const int base = (p >> 5) * PITCH + (p & 31);  // top-left in padded
      float a = nb;
      #pragma unroll
      for (int c2 = 0; c2 < 3; ++c2) {
        #pragma unroll
        for (int q = 0; q < 9; ++q)
          a = fmaf(s_xp[c2 * CHSZ + base + (q / 3) * PITCH + (q % 3)],
                   nwr[c2 * 9 + q], a);
      }
      s_xi[co * CHSZ + base + PITCH + 1] = a + s_xp[co * CHSZ + base + PITCH + 1];
    }
  }
  __syncthreads();

  // ---- phase 3: g[wh][k][ci*9+q] = sum_s w[k,s]*xi[ci,patch(s,q)] ----
  const int G  = t >> 4;          // 0..19
  const int ss = t & 15;          // row-pair / spatial sub
  const int wh = G & 1;
  const int kk = G >> 1;
  const float* wsrc = (wh ? A_.std_w[I] : A_.mu_w[I]) + kk * S;

  if constexpr (STRIDE == 1) {
    // thread owns output rows 2ss, 2ss+1; per-ci pass (low reg pressure);
    // w double-buffered (prefetch next 4-col pair before each FMA group).
    const float* wr0 = wsrc + (2 * ss) * 32;
    const float* wr1 = wr0 + 32;
    const int rbase0 = (2 * ss) * PITCH;
    #pragma unroll
    for (int ci = 0; ci < 3; ++ci) {
      const int rb = ci * CHSZ + rbase0;
      float acc[10];
      #pragma unroll
      for (int j = 0; j < 10; ++j) acc[j] = 0.0f;
      float Av[4], Bv[4], Cv[4];
      #pragma unroll
      for (int u = 0; u < 4; ++u) {
        Av[u] = s_xi[rb + u * PITCH + 0];
        Bv[u] = s_xi[rb + u * PITCH + 1];
      }
      float4 wa0 = *(const float4*)(wr0);
      float4 wa1 = *(const float4*)(wr1);
      float4 wb0, wb1;

#define WCOMP(V, L) ((L) == 0 ? (V).x : (L) == 1 ? (V).y : (L) == 2 ? (V).z : (V).w)
#define STEP(X, P, Q, R, W0, W1) { \
    _Pragma("unroll") \
    for (int u = 0; u < 4; ++u) R[u] = s_xi[rb + u * PITCH + (X) + 2]; \
    const float w0c = WCOMP(W0, (X) & 3); \
    const float w1c = WCOMP(W1, (X) & 3); \
    _Pragma("unroll") \
    for (int dy = 0; dy < 3; ++dy) { \
      acc[dy*3+0] = fmaf(w0c, P[dy], fmaf(w1c, P[dy+1], acc[dy*3+0])); \
      acc[dy*3+1] = fmaf(w0c, Q[dy], fmaf(w1c, Q[dy+1], acc[dy*3+1])); \
      acc[dy*3+2] = fmaf(w0c, R[dy], fmaf(w1c, R[dy+1], acc[dy*3+2])); \
    } \
    if (ci == 0) acc[9] += w0c + w1c; \
  }
#define G4(c, P, Q, R, W0, W1, N0, N1, PF) { \
    if (PF) { N0 = *(const float4*)(wr0 + (c) + 4); \
              N1 = *(const float4*)(wr1 + (c) + 4); } \
    STEP((c)+0, P, Q, R, W0, W1) STEP((c)+1, Q, R, P, W0, W1) \
    STEP((c)+2, R, P, Q, W0, W1) STEP((c)+3, P, Q, R, W0, W1) \
  }

      G4(0,  Av, Bv, Cv, wa0, wa1, wb0, wb1, 1)
      G4(4,  Bv, Cv, Av, wb0, wb1, wa0, wa1, 1)
      G4(8,  Cv, Av, Bv, wa0, wa1, wb0, wb1, 1)
      G4(12, Av, Bv, Cv, wb0, wb1, wa0, wa1, 1)
      G4(16, Bv, Cv, Av, wa0, wa1, wb0, wb1, 1)
      G4(20, Cv, Av, Bv, wb0, wb1, wa0, wa1, 1)
      G4(24, Av, Bv, Cv, wa0, wa1, wb0, wb1, 1)
      G4(28, Bv, Cv, Av, wb0, wb1, wa0, wa1, 0)

#undef G4
#undef STEP
#undef WCOMP
      // reduce across the 16 row-pair lanes and retire this ci's acc
      #pragma unroll
      for (int j = 0; j < 9; ++j) {
        float v = acc[j];
        v += __shfl_xor(v, 1, 64);
        v += __shfl_xor(v, 2, 64);
        v += __shfl_xor(v, 4, 64);
        v += __shfl_xor(v, 8, 64);
        acc[j] = v;
      }
      if (ci == 0) {
        float v = acc[9];
        v += __shfl_xor(v, 1, 64);
        v += __shfl_xor(v, 2, 64);
        v += __shfl_xor(v, 4, 64);
        v += __shfl_xor(v, 8, 64);
        acc[9] = v;
      }
      if (ss == 0) {
        #pragma unroll
        for (int j = 0; j < 9; ++j) s_g[(wh * 10 + kk) * 27 + ci * 9 + j] = acc[j];
        if (ci == 0) s_rs[wh * 10 + kk] = acc[9];
      }
    }
  } else {
    constexpr int PER = S / 16;          // 16 / 4 / 1
    #pragma unroll
    for (int ci = 0; ci < 3; ++ci) {
      float acc[10];
      #pragma unroll
      for (int j = 0; j < 10; ++j) acc[j] = 0.0f;
      #pragma unroll
      for (int u = 0; u < PER; ++u) {
        const int s  = ss * PER + u;
        const int yo = s / Wd, xo = s % Wd;
        const float wx = wsrc[s];
        #pragma unroll
        for (int dy = 0; dy < 3; ++dy) {
          const int base = ci * CHSZ + (yo * STRIDE + dy + 1) * PITCH + (xo * STRIDE + 1);
          #pragma unroll
          for (int dx = 0; dx < 3; ++dx)
            acc[dy * 3 + dx] = fmaf(wx, s_xi[base + dx], acc[dy * 3 + dx]);
        }
        if (ci == 0) acc[9] += wx;
      }
      #pragma unroll
      for (int j = 0; j < 9; ++j) {
        float v = acc[j];
        v += __shfl_xor(v, 1, 64);
        v += __shfl_xor(v, 2, 64);
        v += __shfl_xor(v, 4, 64);
        v += __shfl_xor(v, 8, 64);
        acc[j] = v;
      }
      if (ci == 0) {
        float v = acc[9];
        v += __shfl_xor(v, 1, 64);
        v += __shfl_xor(v, 2, 64);
        v += __shfl_xor(v, 4, 64);
        v += __shfl_xor(v, 8, 64);
        acc[9] = v;
      }
      if (ss == 0) {
        #pragma unroll
        for (int j = 0; j < 9; ++j) s_g[(wh * 10 + kk) * 27 + ci * 9 + j] = acc[j];
        if (ci == 0) s_rs[wh * 10 + kk] = acc[9];
      }
    }
  }
  __syncthreads();

  // ---- phase 4a: s_std[k*C+c] for all classes (low pressure) ----
  for (int v = t; v < 10 * C; v += 320) {
    const int k2 = v / C; const int c = v - k2 * C;
    const float* fw = feat_w + c * 27;
    float a2 = 0.0f;
    #pragma unroll
    for (int j = 0; j < 27; ++j) a2 = fmaf(s_g[(10 + k2) * 27 + j], fw[j], a2);
    a2 = fmaf(feat_b[c], s_rs[10 + k2], a2) + A_.std_b[I][k2];
    s_std[v] = a2;
  }
  __syncthreads();

  // ---- phase 4b: mahal — wave g handles classes {g, g+5}, all lanes ----
  {
    const int g  = t >> 6;     // 0..4 (one wave each)
    const int ln = t & 63;
    float m0 = 0.0f, m1 = 0.0f;
    for (int c = ln; c < C; c += 64) {
      {
        const float sd  = s_std[g * C + c];
        const float eps = jax_normal_pt(fk0, fk1, (uint32_t)((b * 10 + g) * C + c));
        m0 = fmaf(sd * sd, eps * eps, m0);
      }
      {
        const float sd  = s_std[(g + 5) * C + c];
        const float eps = jax_normal_pt(fk0, fk1, (uint32_t)((b * 10 + g + 5) * C + c));
        m1 = fmaf(sd * sd, eps * eps, m1);
      }
    }
    #pragma unroll
    for (int off = 32; off > 0; off >>= 1) {
      m0 += __shfl_down(m0, off, 64);
      m1 += __shfl_down(m1, off, 64);
    }
    if (ln == 0) { s_pt[g] = m0; s_pt[g + 5] = m1; }
  }
  __syncthreads();
  if (t == 0) {
    float best = -INFINITY; int bi = 0;
    #pragma unroll
    for (int k2 = 0; k2 < 10; ++k2) {
      float m = -0.5f * s_pt[k2];
      if (m > best) { best = m; bi = k2; }
    }
    A_.scores[b * 5 + I] = best;
    *s_idx = bi;
  }
  __syncthreads();

  // ---- phase 5: outputs (mean recomputed for argmax class; std from LDS) --
  const int idx = *s_idx;
  for (int c = t; c < C; c += 320) {
    const float* fw = feat_w + c * 27;
    float a1 = 0.0f;
    #pragma unroll
    for (int j = 0; j < 27; ++j) a1 = fmaf(s_g[idx * 27 + j], fw[j], a1);
    a1 = fmaf(feat_b[c], s_rs[idx], a1) + A_.mu_b[I][idx];
    A_.mean_out[I][(size_t)b * C + c] = a1;
    A_.std_out[I][(size_t)b * C + c]  = s_std[idx * C + c];
  }
}

__global__ __launch_bounds__(320)
void ood_all(OodArgs A_) {
  __shared__ float smem[SMEM_FLOATS];
  switch (blockIdx.y) {
    case 0: stage_body<0,  64, 1024, 1>(A_, smem); break;
    case 1: stage_body<1,  64, 1024, 1>(A_, smem); break;
    case 2: stage_body<2, 128,  256, 2>(A_, smem); break;
    case 3: stage_body<3, 256,   64, 4>(A_, smem); break;
    default: stage_body<4, 512,  16, 8>(A_, smem); break;
  }
}

__global__ void ood_clf(const float* __restrict__ scores,  // (B,5)
                        const float* __restrict__ clf_w,   // (1,5)
                        const float* __restrict__ clf_b,   // (1,)
                        float* __restrict__ out) {         // (B,)
  int b = blockIdx.x * blockDim.x + threadIdx.x;
  if (b < B_SZ) {
    float acc = clf_b[0];
    #pragma unroll
    for (int i = 0; i < 5; ++i) acc = fmaf(scores[b * 5 + i], clf_w[i], acc);
    out[b] = acc;
  }
}

extern "C" void kernel_launch(void* const* d_in, const int* in_sizes, int n_in,
                              void* d_out, int out_size, void* d_ws, size_t ws_size,
                              hipStream_t stream) {
  (void)in_sizes; (void)n_in; (void)out_size; (void)ws_size;
  const float* clf_w = (const float*)d_in[33];
  const float* clf_b = (const float*)d_in[34];
  float* out    = (float*)d_out;
  float* scores = (float*)d_ws;   // B*5 floats

  OodArgs A_;
  A_.x       = (const float*)d_in[0];
  A_.noise_w = (const float*)d_in[1];
  A_.noise_b = (const float*)d_in[2];
  const size_t NMEAN = 1048576;
  const size_t moff[5] = {1024, 66560, 132096, 263168, 525312};
  for (int i = 0; i < 5; ++i) {
    A_.feat_w[i]   = (const float*)d_in[3 + 6 * i];
    A_.feat_b[i]   = (const float*)d_in[4 + 6 * i];
    A_.mu_w[i]     = (const float*)d_in[5 + 6 * i];
    A_.mu_b[i]     = (const float*)d_in[6 + 6 * i];
    A_.std_w[i]    = (const float*)d_in[7 + 6 * i];
    A_.std_b[i]    = (const float*)d_in[8 + 6 * i];
    A_.mean_out[i] = out + moff[i];
    A_.std_out[i]  = out + moff[i] + NMEAN;
    tf2x32(0u, 42u, 0u, (uint32_t)i, A_.fk0[i], A_.fk1[i]);
  }
  A_.scores = scores;

  ood_all<<<dim3(B_SZ, 5), 320, 0, stream>>>(A_);
  ood_clf<<<(B_SZ + 255) / 256, 256, 0, stream>>>(scores, clf_w, clf_b, out);
}

// Round 9
// 325.534 us; speedup vs baseline: 1.7102x; 1.2673x over previous
//
#include <hip/hip_runtime.h>
#include <cstdint>

#define B_SZ 1024

// ---------------------------------------------------------------------------
// Threefry-2x32 (20 rounds), exactly as jax._src.prng.threefry2x32.
// ---------------------------------------------------------------------------
__host__ __device__ inline void tf2x32(uint32_t k0, uint32_t k1,
                                       uint32_t x0, uint32_t x1,
                                       uint32_t& o0, uint32_t& o1) {
  uint32_t ks2 = 0x1BD11BDAu ^ k0 ^ k1;
#define TF_RND(r) { x0 += x1; x1 = (x1 << (r)) | (x1 >> (32 - (r))); x1 ^= x0; }
  x0 += k0; x1 += k1;
  TF_RND(13) TF_RND(15) TF_RND(26) TF_RND(6)
  x0 += k1; x1 += ks2 + 1u;
  TF_RND(17) TF_RND(29) TF_RND(16) TF_RND(24)
  x0 += ks2; x1 += k0 + 2u;
  TF_RND(13) TF_RND(15) TF_RND(26) TF_RND(6)
  x0 += k0; x1 += k1 + 3u;
  TF_RND(17) TF_RND(29) TF_RND(16) TF_RND(24)
  x0 += k1; x1 += ks2 + 4u;
  TF_RND(13) TF_RND(15) TF_RND(26) TF_RND(6)
  x0 += ks2; x1 += k0 + 5u;
#undef TF_RND
  o0 = x0; o1 = x1;
}

// XLA ErfInv f32 expansion, identical coefficients.
__device__ inline float erfinv_f32(float x) {
  float w = -log1pf(-x * x);
  float p;
  if (w < 5.0f) {
    w -= 2.5f;
    p = 2.81022636e-08f;
    p = fmaf(p, w, 3.43273939e-07f);
    p = fmaf(p, w, -3.5233877e-06f);
    p = fmaf(p, w, -4.39150654e-06f);
    p = fmaf(p, w, 0.00021858087f);
    p = fmaf(p, w, -0.00125372503f);
    p = fmaf(p, w, -0.00417768164f);
    p = fmaf(p, w, 0.246640727f);
    p = fmaf(p, w, 1.50140941f);
  } else {
    w = sqrtf(w) - 3.0f;
    p = -0.000200214257f;
    p = fmaf(p, w, 0.000100950558f);
    p = fmaf(p, w, 0.00134934322f);
    p = fmaf(p, w, -0.00367342844f);
    p = fmaf(p, w, 0.00573950773f);
    p = fmaf(p, w, -0.0076224613f);
    p = fmaf(p, w, 0.00943887047f);
    p = fmaf(p, w, 1.00167406f);
    p = fmaf(p, w, 2.83297682f);
  }
  return p * x;
}

__device__ inline float jax_normal_pt(uint32_t k0, uint32_t k1, uint32_t e) {
  uint32_t o0, o1;
  tf2x32(k0, k1, 0u, e, o0, o1);
  uint32_t bits = o0 ^ o1;
  float f = __uint_as_float((bits >> 9) | 0x3f800000u) - 1.0f;
  const float LO = -0.99999994f;
  float u = fmaxf(LO, fmaf(f, 2.0f, LO));
  return 1.41421356f * erfinv_f32(u);
}

struct OodArgs {
  const float* x;
  const float* noise_w;
  const float* noise_b;
  const float* feat_w[5];
  const float* feat_b[5];
  const float* mu_w[5];
  const float* mu_b[5];
  const float* std_w[5];
  const float* std_b[5];
  float* mean_out[5];
  float* std_out[5];
  float* scores;   // ws[0..5120)
  float* gws;      // ws + 5120: per (b,I) 560 floats: g[540] | rs[20]
  uint32_t fk0[5], fk1[5];
};

// Padded image buffers: 34 rows x pitch 35 per channel (pitch 35 => phase-3
// lane banks are 6*ss mod 32 = 16 distinct banks, conflict-free).
#define PITCH 35
#define CHSZ  (34 * PITCH)   // 1190
#define XSZ   (3 * CHSZ)     // 3570

// Kernel A LDS (floats)
#define A_XP   0             // 3570
#define A_XI   3570          // 3570
#define A_NW   7140          // 81
#define A_NB   7221          // 3
#define A_SMEM 7224

// ---------------------------------------------------------------------------
// KERNEL A: phases 1-3 only (conv + g-reduction). Low register pressure by
// construction; writes g/rs blob to ws.
// ---------------------------------------------------------------------------
template<int I, int S, int STRIDE>
__device__ __forceinline__ void stageA(const OodArgs& A_, float* smem) {
  constexpr int Wd = 32 / STRIDE;

  const int b = blockIdx.x;
  const int t = threadIdx.x;

  float* s_xp = smem + A_XP;
  float* s_xi = smem + A_XI;
  float* s_nw = smem + A_NW;
  float* s_nb = smem + A_NB;

  // ---- phase 1: zero padded buffers, load x[b] interior, weights ----
  for (int p = t; p < 2 * XSZ; p += 320) smem[p] = 0.0f;
  if (t < 81) s_nw[t] = A_.noise_w[81 * I + t];
  if (t < 3)  s_nb[t] = A_.noise_b[3 * I + t];
  __syncthreads();
  const float* xb = A_.x + (size_t)b * 3072;
  for (int p = t; p < 3072; p += 320) {
    int ci = p >> 10; int rr = p & 1023; int yy = rr >> 5; int xx = rr & 31;
    s_xp[ci * CHSZ + (yy + 1) * PITCH + (xx + 1)] = xb[p];
  }
  __syncthreads();

  // ---- phase 2: xi = x + conv3x3(x, noise_w); branch-free via padding ----
  #pragma unroll
  for (int co = 0; co < 3; ++co) {
    float nwr[27];
    #pragma unroll
    for (int j = 0; j < 27; ++j) nwr[j] = s_nw[co * 27 + j];
    const float nb = s_nb[co];
    for (int p = t; p < 1024; p += 320) {
      const int base = (p >> 5) * PITCH + (p & 31);
      float a = nb;
      #pragma unroll
      for (int c2 = 0; c2 < 3; ++c2) {
        #pragma unroll
        for (int q = 0; q < 9; ++q)
          a = fmaf(s_xp[c2 * CHSZ + base + (q / 3) * PITCH + (q % 3)],
                   nwr[c2 * 9 + q], a);
      }
      s_xi[co * CHSZ + base + PITCH + 1] = a + s_xp[co * CHSZ + base + PITCH + 1];
    }
  }
  __syncthreads();

  // ---- phase 3: g[wh][k][ci*9+q] = sum_s w[k,s]*xi[ci,patch(s,q)] ----
  const int G  = t >> 4;          // 0..19
  const int ss = t & 15;          // row-pair / spatial sub
  const int wh = G & 1;
  const int kk = G >> 1;
  const float* wsrc = (wh ? A_.std_w[I] : A_.mu_w[I]) + kk * S;
  float* gdst = A_.gws + (size_t)(b * 5 + I) * 560;

  if constexpr (STRIDE == 1) {
    const float* wr0 = wsrc + (2 * ss) * 32;
    const float* wr1 = wr0 + 32;
    const int rbase0 = (2 * ss) * PITCH;
    #pragma unroll
    for (int ci = 0; ci < 3; ++ci) {
      const int rb = ci * CHSZ + rbase0;
      float acc[10];
      #pragma unroll
      for (int j = 0; j < 10; ++j) acc[j] = 0.0f;
      float Av[4], Bv[4], Cv[4];
      #pragma unroll
      for (int u = 0; u < 4; ++u) {
        Av[u] = s_xi[rb + u * PITCH + 0];
        Bv[u] = s_xi[rb + u * PITCH + 1];
      }
      float4 wa0 = *(const float4*)(wr0);
      float4 wa1 = *(const float4*)(wr1);
      float4 wb0, wb1;

#define WCOMP(V, L) ((L) == 0 ? (V).x : (L) == 1 ? (V).y : (L) == 2 ? (V).z : (V).w)
#define STEP(X, P, Q, R, W0, W1) { \
    _Pragma("unroll") \
    for (int u = 0; u < 4; ++u) R[u] = s_xi[rb + u * PITCH + (X) + 2]; \
    const float w0c = WCOMP(W0, (X) & 3); \
    const float w1c = WCOMP(W1, (X) & 3); \
    _Pragma("unroll") \
    for (int dy = 0; dy < 3; ++dy) { \
      acc[dy*3+0] = fmaf(w0c, P[dy], fmaf(w1c, P[dy+1], acc[dy*3+0])); \
      acc[dy*3+1] = fmaf(w0c, Q[dy], fmaf(w1c, Q[dy+1], acc[dy*3+1])); \
      acc[dy*3+2] = fmaf(w0c, R[dy], fmaf(w1c, R[dy+1], acc[dy*3+2])); \
    } \
    if (ci == 0) acc[9] += w0c + w1c; \
  }
#define G4(c, P, Q, R, W0, W1, N0, N1, PF) { \
    if (PF) { N0 = *(const float4*)(wr0 + (c) + 4); \
              N1 = *(const float4*)(wr1 + (c) + 4); } \
    STEP((c)+0, P, Q, R, W0, W1) STEP((c)+1, Q, R, P, W0, W1) \
    STEP((c)+2, R, P, Q, W0, W1) STEP((c)+3, P, Q, R, W0, W1) \
  }

      G4(0,  Av, Bv, Cv, wa0, wa1, wb0, wb1, 1)
      G4(4,  Bv, Cv, Av, wb0, wb1, wa0, wa1, 1)
      G4(8,  Cv, Av, Bv, wa0, wa1, wb0, wb1, 1)
      G4(12, Av, Bv, Cv, wb0, wb1, wa0, wa1, 1)
      G4(16, Bv, Cv, Av, wa0, wa1, wb0, wb1, 1)
      G4(20, Cv, Av, Bv, wb0, wb1, wa0, wa1, 1)
      G4(24, Av, Bv, Cv, wa0, wa1, wb0, wb1, 1)
      G4(28, Bv, Cv, Av, wb0, wb1, wa0, wa1, 0)

#undef G4
#undef STEP
#undef WCOMP
      #pragma unroll
      for (int j = 0; j < 10; ++j) {
        float v = acc[j];
        v += __shfl_xor(v, 1, 64);
        v += __shfl_xor(v, 2, 64);
        v += __shfl_xor(v, 4, 64);
        v += __shfl_xor(v, 8, 64);
        acc[j] = v;
      }
      if (ss == 0) {
        #pragma unroll
        for (int j = 0; j < 9; ++j)
          gdst[(wh * 10 + kk) * 27 + ci * 9 + j] = acc[j];
        if (ci == 0) gdst[540 + wh * 10 + kk] = acc[9];
      }
    }
  } else {
    constexpr int PER = S / 16;          // 16 / 4 / 1
    #pragma unroll
    for (int ci = 0; ci < 3; ++ci) {
      float acc[10];
      #pragma unroll
      for (int j = 0; j < 10; ++j) acc[j] = 0.0f;
      #pragma unroll
      for (int u = 0; u < PER; ++u) {
        const int s  = ss * PER + u;
        const int yo = s / Wd, xo = s % Wd;
        const float wx = wsrc[s];
        #pragma unroll
        for (int dy = 0; dy < 3; ++dy) {
          const int base = ci * CHSZ + (yo * STRIDE + dy + 1) * PITCH + (xo * STRIDE + 1);
          #pragma unroll
          for (int dx = 0; dx < 3; ++dx)
            acc[dy * 3 + dx] = fmaf(wx, s_xi[base + dx], acc[dy * 3 + dx]);
        }
        if (ci == 0) acc[9] += wx;
      }
      #pragma unroll
      for (int j = 0; j < 10; ++j) {
        float v = acc[j];
        v += __shfl_xor(v, 1, 64);
        v += __shfl_xor(v, 2, 64);
        v += __shfl_xor(v, 4, 64);
        v += __shfl_xor(v, 8, 64);
        acc[j] = v;
      }
      if (ss == 0) {
        #pragma unroll
        for (int j = 0; j < 9; ++j)
          gdst[(wh * 10 + kk) * 27 + ci * 9 + j] = acc[j];
        if (ci == 0) gdst[540 + wh * 10 + kk] = acc[9];
      }
    }
  }
}

__global__ __launch_bounds__(320)
void ood_a(OodArgs A_) {
  __shared__ float smem[A_SMEM];
  switch (blockIdx.y) {
    case 0: stageA<0, 1024, 1>(A_, smem); break;
    case 1: stageA<1, 1024, 1>(A_, smem); break;
    case 2: stageA<2,  256, 2>(A_, smem); break;
    case 3: stageA<3,   64, 4>(A_, smem); break;
    default: stageA<4,   16, 8>(A_, smem); break;
  }
}

// ---------------------------------------------------------------------------
// KERNEL B: phases 4a/4b/5 (std, mahal+RNG, argmax, outputs).
// ---------------------------------------------------------------------------
template<int I, int C>
__device__ __forceinline__ void stageB(const OodArgs& A_, float* smem) {
  const int b = blockIdx.x;
  const int t = threadIdx.x;

  float* s_g   = smem;             // 540
  float* s_rs  = smem + 540;       // 20
  float* s_std = smem + 560;       // 10*C
  float* s_pt  = smem + 560 + 10 * C;  // 10
  int*   s_idx = (int*)(smem + 570 + 10 * C);

  const float* feat_w = A_.feat_w[I];
  const float* feat_b = A_.feat_b[I];
  const uint32_t fk0 = A_.fk0[I], fk1 = A_.fk1[I];

  const float* gsrc = A_.gws + (size_t)(b * 5 + I) * 560;
  for (int p = t; p < 560; p += 320) smem[p] = gsrc[p];
  __syncthreads();

  // ---- phase 4a: s_std[k*C+c] for all classes ----
  for (int v = t; v < 10 * C; v += 320) {
    const int k2 = v / C; const int c = v - k2 * C;
    const float* fw = feat_w + c * 27;
    float a2 = 0.0f;
    #pragma unroll
    for (int j = 0; j < 27; ++j) a2 = fmaf(s_g[(10 + k2) * 27 + j], fw[j], a2);
    a2 = fmaf(feat_b[c], s_rs[10 + k2], a2) + A_.std_b[I][k2];
    s_std[v] = a2;
  }
  __syncthreads();

  // ---- phase 4b: mahal — wave g handles classes {g, g+5}, all lanes ----
  {
    const int g  = t >> 6;     // 0..4
    const int ln = t & 63;
    float m0 = 0.0f, m1 = 0.0f;
    for (int c = ln; c < C; c += 64) {
      {
        const float sd  = s_std[g * C + c];
        const float eps = jax_normal_pt(fk0, fk1, (uint32_t)((b * 10 + g) * C + c));
        m0 = fmaf(sd * sd, eps * eps, m0);
      }
      {
        const float sd  = s_std[(g + 5) * C + c];
        const float eps = jax_normal_pt(fk0, fk1, (uint32_t)((b * 10 + g + 5) * C + c));
        m1 = fmaf(sd * sd, eps * eps, m1);
      }
    }
    #pragma unroll
    for (int off = 32; off > 0; off >>= 1) {
      m0 += __shfl_down(m0, off, 64);
      m1 += __shfl_down(m1, off, 64);
    }
    if (ln == 0) { s_pt[g] = m0; s_pt[g + 5] = m1; }
  }
  __syncthreads();
  if (t == 0) {
    float best = -INFINITY; int bi = 0;
    #pragma unroll
    for (int k2 = 0; k2 < 10; ++k2) {
      float m = -0.5f * s_pt[k2];
      if (m > best) { best = m; bi = k2; }
    }
    A_.scores[b * 5 + I] = best;
    *s_idx = bi;
  }
  __syncthreads();

  // ---- phase 5: outputs (mean recomputed for argmax class; std from LDS) --
  const int idx = *s_idx;
  for (int c = t; c < C; c += 320) {
    const float* fw = feat_w + c * 27;
    float a1 = 0.0f;
    #pragma unroll
    for (int j = 0; j < 27; ++j) a1 = fmaf(s_g[idx * 27 + j], fw[j], a1);
    a1 = fmaf(feat_b[c], s_rs[idx], a1) + A_.mu_b[I][idx];
    A_.mean_out[I][(size_t)b * C + c] = a1;
    A_.std_out[I][(size_t)b * C + c]  = s_std[idx * C + c];
  }
}

__global__ __launch_bounds__(320)
void ood_b(OodArgs A_) {
  __shared__ float smem[571 + 5120];   // worst case C=512
  switch (blockIdx.y) {
    case 0: stageB<0,  64>(A_, smem); break;
    case 1: stageB<1,  64>(A_, smem); break;
    case 2: stageB<2, 128>(A_, smem); break;
    case 3: stageB<3, 256>(A_, smem); break;
    default: stageB<4, 512>(A_, smem); break;
  }
}

__global__ void ood_clf(const float* __restrict__ scores,  // (B,5)
                        const float* __restrict__ clf_w,   // (1,5)
                        const float* __restrict__ clf_b,   // (1,)
                        float* __restrict__ out) {         // (B,)
  int b = blockIdx.x * blockDim.x + threadIdx.x;
  if (b < B_SZ) {
    float acc = clf_b[0];
    #pragma unroll
    for (int i = 0; i < 5; ++i) acc = fmaf(scores[b * 5 + i], clf_w[i], acc);
    out[b] = acc;
  }
}

extern "C" void kernel_launch(void* const* d_in, const int* in_sizes, int n_in,
                              void* d_out, int out_size, void* d_ws, size_t ws_size,
                              hipStream_t stream) {
  (void)in_sizes; (void)n_in; (void)out_size; (void)ws_size;
  const float* clf_w = (const float*)d_in[33];
  const float* clf_b = (const float*)d_in[34];
  float* out = (float*)d_out;
  float* ws  = (float*)d_ws;   // scores[5120] | g-blobs[5120*560]

  OodArgs A_;
  A_.x       = (const float*)d_in[0];
  A_.noise_w = (const float*)d_in[1];
  A_.noise_b = (const float*)d_in[2];
  const size_t NMEAN = 1048576;
  const size_t moff[5] = {1024, 66560, 132096, 263168, 525312};
  for (int i = 0; i < 5; ++i) {
    A_.feat_w[i]   = (const float*)d_in[3 + 6 * i];
    A_.feat_b[i]   = (const float*)d_in[4 + 6 * i];
    A_.mu_w[i]     = (const float*)d_in[5 + 6 * i];
    A_.mu_b[i]     = (const float*)d_in[6 + 6 * i];
    A_.std_w[i]    = (const float*)d_in[7 + 6 * i];
    A_.std_b[i]    = (const float*)d_in[8 + 6 * i];
    A_.mean_out[i] = out + moff[i];
    A_.std_out[i]  = out + moff[i] + NMEAN;
    tf2x32(0u, 42u, 0u, (uint32_t)i, A_.fk0[i], A_.fk1[i]);
  }
  A_.scores = ws;
  A_.gws    = ws + 5120;

  ood_a<<<dim3(B_SZ, 5), 320, 0, stream>>>(A_);
  ood_b<<<dim3(B_SZ, 5), 320, 0, stream>>>(A_);
  ood_clf<<<(B_SZ + 255) / 256, 256, 0, stream>>>(A_.scores, clf_w, clf_b, out);
}

// Round 10
// 323.437 us; speedup vs baseline: 1.7213x; 1.0065x over previous
//
#include <hip/hip_runtime.h>
#include <cstdint>

#define B_SZ 1024

// ---------------------------------------------------------------------------
// Threefry-2x32 (20 rounds), exactly as jax._src.prng.threefry2x32.
// ---------------------------------------------------------------------------
__host__ __device__ inline void tf2x32(uint32_t k0, uint32_t k1,
                                       uint32_t x0, uint32_t x1,
                                       uint32_t& o0, uint32_t& o1) {
  uint32_t ks2 = 0x1BD11BDAu ^ k0 ^ k1;
#define TF_RND(r) { x0 += x1; x1 = (x1 << (r)) | (x1 >> (32 - (r))); x1 ^= x0; }
  x0 += k0; x1 += k1;
  TF_RND(13) TF_RND(15) TF_RND(26) TF_RND(6)
  x0 += k1; x1 += ks2 + 1u;
  TF_RND(17) TF_RND(29) TF_RND(16) TF_RND(24)
  x0 += ks2; x1 += k0 + 2u;
  TF_RND(13) TF_RND(15) TF_RND(26) TF_RND(6)
  x0 += k0; x1 += k1 + 3u;
  TF_RND(17) TF_RND(29) TF_RND(16) TF_RND(24)
  x0 += k1; x1 += ks2 + 4u;
  TF_RND(13) TF_RND(15) TF_RND(26) TF_RND(6)
  x0 += ks2; x1 += k0 + 5u;
#undef TF_RND
  o0 = x0; o1 = x1;
}

// XLA ErfInv f32 expansion, identical coefficients.
__device__ inline float erfinv_f32(float x) {
  float w = -log1pf(-x * x);
  float p;
  if (w < 5.0f) {
    w -= 2.5f;
    p = 2.81022636e-08f;
    p = fmaf(p, w, 3.43273939e-07f);
    p = fmaf(p, w, -3.5233877e-06f);
    p = fmaf(p, w, -4.39150654e-06f);
    p = fmaf(p, w, 0.00021858087f);
    p = fmaf(p, w, -0.00125372503f);
    p = fmaf(p, w, -0.00417768164f);
    p = fmaf(p, w, 0.246640727f);
    p = fmaf(p, w, 1.50140941f);
  } else {
    w = sqrtf(w) - 3.0f;
    p = -0.000200214257f;
    p = fmaf(p, w, 0.000100950558f);
    p = fmaf(p, w, 0.00134934322f);
    p = fmaf(p, w, -0.00367342844f);
    p = fmaf(p, w, 0.00573950773f);
    p = fmaf(p, w, -0.0076224613f);
    p = fmaf(p, w, 0.00943887047f);
    p = fmaf(p, w, 1.00167406f);
    p = fmaf(p, w, 2.83297682f);
  }
  return p * x;
}

__device__ inline float jax_normal_pt(uint32_t k0, uint32_t k1, uint32_t e) {
  uint32_t o0, o1;
  tf2x32(k0, k1, 0u, e, o0, o1);
  uint32_t bits = o0 ^ o1;
  float f = __uint_as_float((bits >> 9) | 0x3f800000u) - 1.0f;
  const float LO = -0.99999994f;
  float u = fmaxf(LO, fmaf(f, 2.0f, LO));
  return 1.41421356f * erfinv_f32(u);
}

struct OodArgs {
  const float* x;
  const float* noise_w;
  const float* noise_b;
  const float* feat_w[5];
  const float* feat_b[5];
  const float* mu_w[5];
  const float* mu_b[5];
  const float* std_w[5];
  const float* std_b[5];
  float* mean_out[5];
  float* std_out[5];
  float* scores;   // ws[0..5120)
  float* gws;      // ws + 5120: per (b,I) 560 floats: g[540] | rs[20]
  uint32_t fk0[5], fk1[5];
};

// Padded image buffers: 34 rows x pitch 35 per channel (pitch 35 => phase-3
// lane banks are 6*ss mod 32 = 16 distinct banks, conflict-free).
#define PITCH 35
#define CHSZ  (34 * PITCH)   // 1190
#define XSZ   (3 * CHSZ)     // 3570

// Kernel A LDS (floats)
#define A_XP   0             // 3570
#define A_XI   3570          // 3570
#define A_NW   7140          // 81
#define A_NB   7221          // 3
#define A_SMEM 7224

// ---------------------------------------------------------------------------
// KERNEL A: phases 1-3 (conv + g-reduction), g/rs blob to ws.
// Phase 3 stride-1 is software-pipelined one 4-column group ahead: the next
// group's 16 window values + w float4 pair are issued before the current
// group's FMAs, hiding LDS/L2 latency under ~150 cyc of FMA issue.
// ---------------------------------------------------------------------------
template<int I, int S, int STRIDE>
__device__ __forceinline__ void stageA(const OodArgs& A_, float* smem) {
  constexpr int Wd = 32 / STRIDE;

  const int b = blockIdx.x;
  const int t = threadIdx.x;

  float* s_xp = smem + A_XP;
  float* s_xi = smem + A_XI;
  float* s_nw = smem + A_NW;
  float* s_nb = smem + A_NB;

  // ---- phase 1: zero padded buffers, load x[b] interior, weights ----
  for (int p = t; p < 2 * XSZ; p += 320) smem[p] = 0.0f;
  if (t < 81) s_nw[t] = A_.noise_w[81 * I + t];
  if (t < 3)  s_nb[t] = A_.noise_b[3 * I + t];
  __syncthreads();
  const float* xb = A_.x + (size_t)b * 3072;
  for (int p = t; p < 3072; p += 320) {
    int ci = p >> 10; int rr = p & 1023; int yy = rr >> 5; int xx = rr & 31;
    s_xp[ci * CHSZ + (yy + 1) * PITCH + (xx + 1)] = xb[p];
  }
  __syncthreads();

  // ---- phase 2: xi = x + conv3x3(x, noise_w); branch-free via padding ----
  #pragma unroll
  for (int co = 0; co < 3; ++co) {
    float nwr[27];
    #pragma unroll
    for (int j = 0; j < 27; ++j) nwr[j] = s_nw[co * 27 + j];
    const float nb = s_nb[co];
    for (int p = t; p < 1024; p += 320) {
      const int base = (p >> 5) * PITCH + (p & 31);
      float a = nb;
      #pragma unroll
      for (int c2 = 0; c2 < 3; ++c2) {
        #pragma unroll
        for (int q = 0; q < 9; ++q)
          a = fmaf(s_xp[c2 * CHSZ + base + (q / 3) * PITCH + (q % 3)],
                   nwr[c2 * 9 + q], a);
      }
      s_xi[co * CHSZ + base + PITCH + 1] = a + s_xp[co * CHSZ + base + PITCH + 1];
    }
  }
  __syncthreads();

  // ---- phase 3: g[wh][k][ci*9+q] = sum_s w[k,s]*xi[ci,patch(s,q)] ----
  const int G  = t >> 4;          // 0..19
  const int ss = t & 15;          // row-pair / spatial sub
  const int wh = G & 1;
  const int kk = G >> 1;
  const float* wsrc = (wh ? A_.std_w[I] : A_.mu_w[I]) + kk * S;
  float* gdst = A_.gws + (size_t)(b * 5 + I) * 560;

  if constexpr (STRIDE == 1) {
    const float* wr0 = wsrc + (2 * ss) * 32;
    const float* wr1 = wr0 + 32;
    const int rbase0 = (2 * ss) * PITCH;
    #pragma unroll
    for (int ci = 0; ci < 3; ++ci) {
      const int rb = ci * CHSZ + rbase0;
      float acc[10];
      #pragma unroll
      for (int j = 0; j < 10; ++j) acc[j] = 0.0f;
      // persistent 2-col tail + double-buffered 4-col window blocks
      float L0[4], L1[4], Bf[4][4], Nf[4][4];
      #pragma unroll
      for (int u = 0; u < 4; ++u) {
        L0[u] = s_xi[rb + u * PITCH + 0];
        L1[u] = s_xi[rb + u * PITCH + 1];
      }
      #pragma unroll
      for (int cc = 0; cc < 4; ++cc)
        #pragma unroll
        for (int u = 0; u < 4; ++u)
          Bf[cc][u] = s_xi[rb + u * PITCH + 2 + cc];
      float4 wa0 = *(const float4*)(wr0);
      float4 wa1 = *(const float4*)(wr1);
      float4 wb0, wb1;

#define STEPX(P, Q, R, W0S, W1S) { \
    const float w0c = (W0S); \
    const float w1c = (W1S); \
    _Pragma("unroll") \
    for (int dy = 0; dy < 3; ++dy) { \
      acc[dy*3+0] = fmaf(w0c, P[dy], fmaf(w1c, P[dy+1], acc[dy*3+0])); \
      acc[dy*3+1] = fmaf(w0c, Q[dy], fmaf(w1c, Q[dy+1], acc[dy*3+1])); \
      acc[dy*3+2] = fmaf(w0c, R[dy], fmaf(w1c, R[dy+1], acc[dy*3+2])); \
    } \
    if (ci == 0) acc[9] += w0c + w1c; \
  }
// GROUPX(g): outputs 4g..4g+3 from L0(=col 4g), L1(=col 4g+1), CUR(=cols
// 4g+2..4g+5).  PF: prefetch NXT (cols 4g+6..4g+9) + next w pair FIRST so
// their latency hides under the 76 FMAs below.
#define GROUPX(g, CUR, NXT, W0, W1, NW0, NW1, PF) { \
    if (PF) { \
      _Pragma("unroll") \
      for (int cc = 0; cc < 4; ++cc) \
        _Pragma("unroll") \
        for (int u = 0; u < 4; ++u) \
          NXT[cc][u] = s_xi[rb + u * PITCH + 6 + 4 * (g) + cc]; \
      NW0 = *(const float4*)(wr0 + 4 * (g) + 4); \
      NW1 = *(const float4*)(wr1 + 4 * (g) + 4); \
    } \
    STEPX(L0,     L1,     CUR[0], (W0).x, (W1).x) \
    STEPX(L1,     CUR[0], CUR[1], (W0).y, (W1).y) \
    STEPX(CUR[0], CUR[1], CUR[2], (W0).z, (W1).z) \
    STEPX(CUR[1], CUR[2], CUR[3], (W0).w, (W1).w) \
    _Pragma("unroll") \
    for (int u = 0; u < 4; ++u) { L0[u] = CUR[2][u]; L1[u] = CUR[3][u]; } \
  }

      GROUPX(0, Bf, Nf, wa0, wa1, wb0, wb1, 1)
      GROUPX(1, Nf, Bf, wb0, wb1, wa0, wa1, 1)
      GROUPX(2, Bf, Nf, wa0, wa1, wb0, wb1, 1)
      GROUPX(3, Nf, Bf, wb0, wb1, wa0, wa1, 1)
      GROUPX(4, Bf, Nf, wa0, wa1, wb0, wb1, 1)
      GROUPX(5, Nf, Bf, wb0, wb1, wa0, wa1, 1)
      GROUPX(6, Bf, Nf, wa0, wa1, wb0, wb1, 1)
      GROUPX(7, Nf, Bf, wb0, wb1, wa0, wa1, 0)

#undef GROUPX
#undef STEPX
      #pragma unroll
      for (int j = 0; j < 10; ++j) {
        float v = acc[j];
        v += __shfl_xor(v, 1, 64);
        v += __shfl_xor(v, 2, 64);
        v += __shfl_xor(v, 4, 64);
        v += __shfl_xor(v, 8, 64);
        acc[j] = v;
      }
      if (ss == 0) {
        #pragma unroll
        for (int j = 0; j < 9; ++j)
          gdst[(wh * 10 + kk) * 27 + ci * 9 + j] = acc[j];
        if (ci == 0) gdst[540 + wh * 10 + kk] = acc[9];
      }
    }
  } else {
    constexpr int PER = S / 16;          // 16 / 4 / 1
    #pragma unroll
    for (int ci = 0; ci < 3; ++ci) {
      float acc[10];
      #pragma unroll
      for (int j = 0; j < 10; ++j) acc[j] = 0.0f;
      #pragma unroll
      for (int u = 0; u < PER; ++u) {
        const int s  = ss * PER + u;
        const int yo = s / Wd, xo = s % Wd;
        const float wx = wsrc[s];
        #pragma unroll
        for (int dy = 0; dy < 3; ++dy) {
          const int base = ci * CHSZ + (yo * STRIDE + dy + 1) * PITCH + (xo * STRIDE + 1);
          #pragma unroll
          for (int dx = 0; dx < 3; ++dx)
            acc[dy * 3 + dx] = fmaf(wx, s_xi[base + dx], acc[dy * 3 + dx]);
        }
        if (ci == 0) acc[9] += wx;
      }
      #pragma unroll
      for (int j = 0; j < 10; ++j) {
        float v = acc[j];
        v += __shfl_xor(v, 1, 64);
        v += __shfl_xor(v, 2, 64);
        v += __shfl_xor(v, 4, 64);
        v += __shfl_xor(v, 8, 64);
        acc[j] = v;
      }
      if (ss == 0) {
        #pragma unroll
        for (int j = 0; j < 9; ++j)
          gdst[(wh * 10 + kk) * 27 + ci * 9 + j] = acc[j];
        if (ci == 0) gdst[540 + wh * 10 + kk] = acc[9];
      }
    }
  }
}

__global__ __launch_bounds__(320)
void ood_a(OodArgs A_) {
  __shared__ float smem[A_SMEM];
  switch (blockIdx.y) {
    case 0: stageA<0, 1024, 1>(A_, smem); break;
    case 1: stageA<1, 1024, 1>(A_, smem); break;
    case 2: stageA<2,  256, 2>(A_, smem); break;
    case 3: stageA<3,   64, 4>(A_, smem); break;
    default: stageA<4,   16, 8>(A_, smem); break;
  }
}

// ---------------------------------------------------------------------------
// KERNEL B: phases 4a/4b/5 (std, mahal+RNG, argmax, outputs).
// ---------------------------------------------------------------------------
template<int I, int C>
__device__ __forceinline__ void stageB(const OodArgs& A_, float* smem) {
  const int b = blockIdx.x;
  const int t = threadIdx.x;

  float* s_g   = smem;             // 540
  float* s_rs  = smem + 540;       // 20
  float* s_std = smem + 560;       // 10*C
  float* s_pt  = smem + 560 + 10 * C;  // 10
  int*   s_idx = (int*)(smem + 570 + 10 * C);

  const float* feat_w = A_.feat_w[I];
  const float* feat_b = A_.feat_b[I];
  const uint32_t fk0 = A_.fk0[I], fk1 = A_.fk1[I];

  const float* gsrc = A_.gws + (size_t)(b * 5 + I) * 560;
  for (int p = t; p < 560; p += 320) smem[p] = gsrc[p];
  __syncthreads();

  // ---- phase 4a: s_std[k*C+c] for all classes ----
  for (int v = t; v < 10 * C; v += 320) {
    const int k2 = v / C; const int c = v - k2 * C;
    const float* fw = feat_w + c * 27;
    float a2 = 0.0f;
    #pragma unroll
    for (int j = 0; j < 27; ++j) a2 = fmaf(s_g[(10 + k2) * 27 + j], fw[j], a2);
    a2 = fmaf(feat_b[c], s_rs[10 + k2], a2) + A_.std_b[I][k2];
    s_std[v] = a2;
  }
  __syncthreads();

  // ---- phase 4b: mahal — wave g handles classes {g, g+5}, all lanes ----
  {
    const int g  = t >> 6;     // 0..4
    const int ln = t & 63;
    float m0 = 0.0f, m1 = 0.0f;
    for (int c = ln; c < C; c += 64) {
      {
        const float sd  = s_std[g * C + c];
        const float eps = jax_normal_pt(fk0, fk1, (uint32_t)((b * 10 + g) * C + c));
        m0 = fmaf(sd * sd, eps * eps, m0);
      }
      {
        const float sd  = s_std[(g + 5) * C + c];
        const float eps = jax_normal_pt(fk0, fk1, (uint32_t)((b * 10 + g + 5) * C + c));
        m1 = fmaf(sd * sd, eps * eps, m1);
      }
    }
    #pragma unroll
    for (int off = 32; off > 0; off >>= 1) {
      m0 += __shfl_down(m0, off, 64);
      m1 += __shfl_down(m1, off, 64);
    }
    if (ln == 0) { s_pt[g] = m0; s_pt[g + 5] = m1; }
  }
  __syncthreads();
  if (t == 0) {
    float best = -INFINITY; int bi = 0;
    #pragma unroll
    for (int k2 = 0; k2 < 10; ++k2) {
      float m = -0.5f * s_pt[k2];
      if (m > best) { best = m; bi = k2; }
    }
    A_.scores[b * 5 + I] = best;
    *s_idx = bi;
  }
  __syncthreads();

  // ---- phase 5: outputs (mean recomputed for argmax class; std from LDS) --
  const int idx = *s_idx;
  for (int c = t; c < C; c += 320) {
    const float* fw = feat_w + c * 27;
    float a1 = 0.0f;
    #pragma unroll
    for (int j = 0; j < 27; ++j) a1 = fmaf(s_g[idx * 27 + j], fw[j], a1);
    a1 = fmaf(feat_b[c], s_rs[idx], a1) + A_.mu_b[I][idx];
    A_.mean_out[I][(size_t)b * C + c] = a1;
    A_.std_out[I][(size_t)b * C + c]  = s_std[idx * C + c];
  }
}

__global__ __launch_bounds__(320)
void ood_b(OodArgs A_) {
  __shared__ float smem[571 + 5120];   // worst case C=512
  switch (blockIdx.y) {
    case 0: stageB<0,  64>(A_, smem); break;
    case 1: stageB<1,  64>(A_, smem); break;
    case 2: stageB<2, 128>(A_, smem); break;
    case 3: stageB<3, 256>(A_, smem); break;
    default: stageB<4, 512>(A_, smem); break;
  }
}

__global__ void ood_clf(const float* __restrict__ scores,  // (B,5)
                        const float* __restrict__ clf_w,   // (1,5)
                        const float* __restrict__ clf_b,   // (1,)
                        float* __restrict__ out) {         // (B,)
  int b = blockIdx.x * blockDim.x + threadIdx.x;
  if (b < B_SZ) {
    float acc = clf_b[0];
    #pragma unroll
    for (int i = 0; i < 5; ++i) acc = fmaf(scores[b * 5 + i], clf_w[i], acc);
    out[b] = acc;
  }
}

extern "C" void kernel_launch(void* const* d_in, const int* in_sizes, int n_in,
                              void* d_out, int out_size, void* d_ws, size_t ws_size,
                              hipStream_t stream) {
  (void)in_sizes; (void)n_in; (void)out_size; (void)ws_size;
  const float* clf_w = (const float*)d_in[33];
  const float* clf_b = (const float*)d_in[34];
  float* out = (float*)d_out;
  float* ws  = (float*)d_ws;   // scores[5120] | g-blobs[5120*560]

  OodArgs A_;
  A_.x       = (const float*)d_in[0];
  A_.noise_w = (const float*)d_in[1];
  A_.noise_b = (const float*)d_in[2];
  const size_t NMEAN = 1048576;
  const size_t moff[5] = {1024, 66560, 132096, 263168, 525312};
  for (int i = 0; i < 5; ++i) {
    A_.feat_w[i]   = (const float*)d_in[3 + 6 * i];
    A_.feat_b[i]   = (const float*)d_in[4 + 6 * i];
    A_.mu_w[i]     = (const float*)d_in[5 + 6 * i];
    A_.mu_b[i]     = (const float*)d_in[6 + 6 * i];
    A_.std_w[i]    = (const float*)d_in[7 + 6 * i];
    A_.std_b[i]    = (const float*)d_in[8 + 6 * i];
    A_.mean_out[i] = out + moff[i];
    A_.std_out[i]  = out + moff[i] + NMEAN;
    tf2x32(0u, 42u, 0u, (uint32_t)i, A_.fk0[i], A_.fk1[i]);
  }
  A_.scores = ws;
  A_.gws    = ws + 5120;

  ood_a<<<dim3(B_SZ, 5), 320, 0, stream>>>(A_);
  ood_b<<<dim3(B_SZ, 5), 320, 0, stream>>>(A_);
  ood_clf<<<(B_SZ + 255) / 256, 256, 0, stream>>>(A_.scores, clf_w, clf_b, out);
}

// Round 11
// 322.428 us; speedup vs baseline: 1.7267x; 1.0031x over previous
//
#include <hip/hip_runtime.h>
#include <cstdint>

#define B_SZ 1024

// ---------------------------------------------------------------------------
// Threefry-2x32 (20 rounds), exactly as jax._src.prng.threefry2x32.
// ---------------------------------------------------------------------------
__host__ __device__ inline void tf2x32(uint32_t k0, uint32_t k1,
                                       uint32_t x0, uint32_t x1,
                                       uint32_t& o0, uint32_t& o1) {
  uint32_t ks2 = 0x1BD11BDAu ^ k0 ^ k1;
#define TF_RND(r) { x0 += x1; x1 = (x1 << (r)) | (x1 >> (32 - (r))); x1 ^= x0; }
  x0 += k0; x1 += k1;
  TF_RND(13) TF_RND(15) TF_RND(26) TF_RND(6)
  x0 += k1; x1 += ks2 + 1u;
  TF_RND(17) TF_RND(29) TF_RND(16) TF_RND(24)
  x0 += ks2; x1 += k0 + 2u;
  TF_RND(13) TF_RND(15) TF_RND(26) TF_RND(6)
  x0 += k0; x1 += k1 + 3u;
  TF_RND(17) TF_RND(29) TF_RND(16) TF_RND(24)
  x0 += k1; x1 += ks2 + 4u;
  TF_RND(13) TF_RND(15) TF_RND(26) TF_RND(6)
  x0 += ks2; x1 += k0 + 5u;
#undef TF_RND
  o0 = x0; o1 = x1;
}

// XLA ErfInv f32 expansion, identical coefficients.
__device__ inline float erfinv_f32(float x) {
  float w = -log1pf(-x * x);
  float p;
  if (w < 5.0f) {
    w -= 2.5f;
    p = 2.81022636e-08f;
    p = fmaf(p, w, 3.43273939e-07f);
    p = fmaf(p, w, -3.5233877e-06f);
    p = fmaf(p, w, -4.39150654e-06f);
    p = fmaf(p, w, 0.00021858087f);
    p = fmaf(p, w, -0.00125372503f);
    p = fmaf(p, w, -0.00417768164f);
    p = fmaf(p, w, 0.246640727f);
    p = fmaf(p, w, 1.50140941f);
  } else {
    w = sqrtf(w) - 3.0f;
    p = -0.000200214257f;
    p = fmaf(p, w, 0.000100950558f);
    p = fmaf(p, w, 0.00134934322f);
    p = fmaf(p, w, -0.00367342844f);
    p = fmaf(p, w, 0.00573950773f);
    p = fmaf(p, w, -0.0076224613f);
    p = fmaf(p, w, 0.00943887047f);
    p = fmaf(p, w, 1.00167406f);
    p = fmaf(p, w, 2.83297682f);
  }
  return p * x;
}

__device__ inline float jax_normal_pt(uint32_t k0, uint32_t k1, uint32_t e) {
  uint32_t o0, o1;
  tf2x32(k0, k1, 0u, e, o0, o1);
  uint32_t bits = o0 ^ o1;
  float f = __uint_as_float((bits >> 9) | 0x3f800000u) - 1.0f;
  const float LO = -0.99999994f;
  float u = fmaxf(LO, fmaf(f, 2.0f, LO));
  return 1.41421356f * erfinv_f32(u);
}

struct OodArgs {
  const float* x;
  const float* noise_w;
  const float* noise_b;
  const float* feat_w[5];
  const float* feat_b[5];
  const float* mu_w[5];
  const float* mu_b[5];
  const float* std_w[5];
  const float* std_b[5];
  float* mean_out[5];
  float* std_out[5];
  float* scores;   // ws[0..5120)
  float* gws;      // ws + 5120: per (b,I) 560 floats: g[540] | rs[20]
  uint32_t fk0[5], fk1[5];
};

// Padded image buffers: 34 rows x pitch 35 per channel (pitch 35 => phase-3
// lane banks are 6*ss mod 32 = 16 distinct banks, conflict-free).
#define PITCH 35
#define CHSZ  (34 * PITCH)   // 1190
#define XSZ   (3 * CHSZ)     // 3570

// Kernel A LDS (floats)
#define A_XP   0             // 3570
#define A_XI   3570          // 3570
#define A_NW   7140          // 81
#define A_NB   7221          // 3
#define A_SMEM 7224

// ---------------------------------------------------------------------------
// KERNEL A: phases 1-3 (conv + g-reduction), g/rs blob to ws.
// Templated on (S, STRIDE) only; stage index i is runtime (uniform) so the
// two stride-1 stages share ONE instantiation (icache).  Live set kept ~50
// VGPRs so the (320,8) bound pins allocation at the 64-reg bucket
// (8 waves/SIMD) WITHOUT spilling -- the occupancy lever this round.
// ---------------------------------------------------------------------------
template<int S, int STRIDE>
__device__ __forceinline__ void stageA(const OodArgs& A_, float* smem, int i) {
  constexpr int Wd = 32 / STRIDE;

  const int b = blockIdx.x;
  const int t = threadIdx.x;

  float* s_xp = smem + A_XP;
  float* s_xi = smem + A_XI;
  float* s_nw = smem + A_NW;
  float* s_nb = smem + A_NB;

  // ---- phase 1: zero padded buffers, load x[b] interior, weights ----
  for (int p = t; p < 2 * XSZ; p += 320) smem[p] = 0.0f;
  if (t < 81) s_nw[t] = A_.noise_w[81 * i + t];
  if (t < 3)  s_nb[t] = A_.noise_b[3 * i + t];
  __syncthreads();
  const float* xb = A_.x + (size_t)b * 3072;
  for (int p = t; p < 3072; p += 320) {
    int ci = p >> 10; int rr = p & 1023; int yy = rr >> 5; int xx = rr & 31;
    s_xp[ci * CHSZ + (yy + 1) * PITCH + (xx + 1)] = xb[p];
  }
  __syncthreads();

  // ---- phase 2: xi = x + conv3x3(x, noise_w); branch-free via padding ----
  #pragma unroll
  for (int co = 0; co < 3; ++co) {
    float nwr[27];
    #pragma unroll
    for (int j = 0; j < 27; ++j) nwr[j] = s_nw[co * 27 + j];
    const float nb = s_nb[co];
    for (int p = t; p < 1024; p += 320) {
      const int base = (p >> 5) * PITCH + (p & 31);
      float a = nb;
      #pragma unroll
      for (int c2 = 0; c2 < 3; ++c2) {
        #pragma unroll
        for (int q = 0; q < 9; ++q)
          a = fmaf(s_xp[c2 * CHSZ + base + (q / 3) * PITCH + (q % 3)],
                   nwr[c2 * 9 + q], a);
      }
      s_xi[co * CHSZ + base + PITCH + 1] = a + s_xp[co * CHSZ + base + PITCH + 1];
    }
  }
  __syncthreads();

  // ---- phase 3: g[wh][k][ci*9+q] = sum_s w[k,s]*xi[ci,patch(s,q)] ----
  const int G  = t >> 4;          // 0..19
  const int ss = t & 15;          // row-pair / spatial sub
  const int wh = G & 1;
  const int kk = G >> 1;
  const float* wsrc = (wh ? A_.std_w[i] : A_.mu_w[i]) + kk * S;
  float* gdst = A_.gws + (size_t)(b * 5 + i) * 560;

  if constexpr (STRIDE == 1) {
    // thread owns output rows 2ss, 2ss+1; row-1 w accessed via +32 imm off.
    const float* wr = wsrc + (2 * ss) * 32;
    const int rbase0 = (2 * ss) * PITCH;
    #pragma unroll
    for (int ci = 0; ci < 3; ++ci) {
      const int rb = ci * CHSZ + rbase0;
      float acc[10];
      #pragma unroll
      for (int j = 0; j < 10; ++j) acc[j] = 0.0f;
      float Av[4], Bv[4], Cv[4];
      #pragma unroll
      for (int u = 0; u < 4; ++u) {
        Av[u] = s_xi[rb + u * PITCH + 0];
        Bv[u] = s_xi[rb + u * PITCH + 1];
      }

#define WCOMP(V, L) ((L) == 0 ? (V).x : (L) == 1 ? (V).y : (L) == 2 ? (V).z : (V).w)
#define STEP(X, P, Q, R, W0, W1) { \
    _Pragma("unroll") \
    for (int u = 0; u < 4; ++u) R[u] = s_xi[rb + u * PITCH + (X) + 2]; \
    const float w0c = WCOMP(W0, (X) & 3); \
    const float w1c = WCOMP(W1, (X) & 3); \
    _Pragma("unroll") \
    for (int dy = 0; dy < 3; ++dy) { \
      acc[dy*3+0] = fmaf(w0c, P[dy], fmaf(w1c, P[dy+1], acc[dy*3+0])); \
      acc[dy*3+1] = fmaf(w0c, Q[dy], fmaf(w1c, Q[dy+1], acc[dy*3+1])); \
      acc[dy*3+2] = fmaf(w0c, R[dy], fmaf(w1c, R[dy+1], acc[dy*3+2])); \
    } \
    if (ci == 0) acc[9] += w0c + w1c; \
  }
#define G4_0(c) { const float4 w0 = *(const float4*)(wr + (c)); \
                  const float4 w1 = *(const float4*)(wr + 32 + (c)); \
    STEP((c)+0, Av, Bv, Cv, w0, w1) STEP((c)+1, Bv, Cv, Av, w0, w1) \
    STEP((c)+2, Cv, Av, Bv, w0, w1) STEP((c)+3, Av, Bv, Cv, w0, w1) }
#define G4_1(c) { const float4 w0 = *(const float4*)(wr + (c)); \
                  const float4 w1 = *(const float4*)(wr + 32 + (c)); \
    STEP((c)+0, Bv, Cv, Av, w0, w1) STEP((c)+1, Cv, Av, Bv, w0, w1) \
    STEP((c)+2, Av, Bv, Cv, w0, w1) STEP((c)+3, Bv, Cv, Av, w0, w1) }
#define G4_2(c) { const float4 w0 = *(const float4*)(wr + (c)); \
                  const float4 w1 = *(const float4*)(wr + 32 + (c)); \
    STEP((c)+0, Cv, Av, Bv, w0, w1) STEP((c)+1, Av, Bv, Cv, w0, w1) \
    STEP((c)+2, Bv, Cv, Av, w0, w1) STEP((c)+3, Cv, Av, Bv, w0, w1) }

      G4_0(0) G4_1(4) G4_2(8) G4_0(12) G4_1(16) G4_2(20) G4_0(24) G4_1(28)

#undef G4_0
#undef G4_1
#undef G4_2
#undef STEP
#undef WCOMP
      #pragma unroll
      for (int j = 0; j < 10; ++j) {
        float v = acc[j];
        v += __shfl_xor(v, 1, 64);
        v += __shfl_xor(v, 2, 64);
        v += __shfl_xor(v, 4, 64);
        v += __shfl_xor(v, 8, 64);
        acc[j] = v;
      }
      if (ss == 0) {
        #pragma unroll
        for (int j = 0; j < 9; ++j)
          gdst[(wh * 10 + kk) * 27 + ci * 9 + j] = acc[j];
        if (ci == 0) gdst[540 + wh * 10 + kk] = acc[9];
      }
    }
  } else {
    constexpr int PER = S / 16;          // 16 / 4 / 1
    #pragma unroll
    for (int ci = 0; ci < 3; ++ci) {
      float acc[10];
      #pragma unroll
      for (int j = 0; j < 10; ++j) acc[j] = 0.0f;
      #pragma unroll
      for (int u = 0; u < PER; ++u) {
        const int s  = ss * PER + u;
        const int yo = s / Wd, xo = s % Wd;
        const float wx = wsrc[s];
        #pragma unroll
        for (int dy = 0; dy < 3; ++dy) {
          const int base = ci * CHSZ + (yo * STRIDE + dy + 1) * PITCH + (xo * STRIDE + 1);
          #pragma unroll
          for (int dx = 0; dx < 3; ++dx)
            acc[dy * 3 + dx] = fmaf(wx, s_xi[base + dx], acc[dy * 3 + dx]);
        }
        if (ci == 0) acc[9] += wx;
      }
      #pragma unroll
      for (int j = 0; j < 10; ++j) {
        float v = acc[j];
        v += __shfl_xor(v, 1, 64);
        v += __shfl_xor(v, 2, 64);
        v += __shfl_xor(v, 4, 64);
        v += __shfl_xor(v, 8, 64);
        acc[j] = v;
      }
      if (ss == 0) {
        #pragma unroll
        for (int j = 0; j < 9; ++j)
          gdst[(wh * 10 + kk) * 27 + ci * 9 + j] = acc[j];
        if (ci == 0) gdst[540 + wh * 10 + kk] = acc[9];
      }
    }
  }
}

__global__ __launch_bounds__(320, 8)
void ood_a(OodArgs A_) {
  __shared__ float smem[A_SMEM];
  const int y = blockIdx.y;
  switch (y) {
    case 0:
    case 1: stageA<1024, 1>(A_, smem, y); break;
    case 2: stageA< 256, 2>(A_, smem, 2); break;
    case 3: stageA<  64, 4>(A_, smem, 3); break;
    default: stageA< 16, 8>(A_, smem, 4); break;
  }
}

// ---------------------------------------------------------------------------
// KERNEL B: phases 4a/4b/5 (std, mahal+RNG, argmax, outputs).
// ---------------------------------------------------------------------------
template<int I, int C>
__device__ __forceinline__ void stageB(const OodArgs& A_, float* smem) {
  const int b = blockIdx.x;
  const int t = threadIdx.x;

  float* s_g   = smem;             // 540
  float* s_rs  = smem + 540;       // 20
  float* s_std = smem + 560;       // 10*C
  float* s_pt  = smem + 560 + 10 * C;  // 10
  int*   s_idx = (int*)(smem + 570 + 10 * C);

  const float* feat_w = A_.feat_w[I];
  const float* feat_b = A_.feat_b[I];
  const uint32_t fk0 = A_.fk0[I], fk1 = A_.fk1[I];

  const float* gsrc = A_.gws + (size_t)(b * 5 + I) * 560;
  for (int p = t; p < 560; p += 320) smem[p] = gsrc[p];
  __syncthreads();

  // ---- phase 4a: s_std[k*C+c] for all classes ----
  for (int v = t; v < 10 * C; v += 320) {
    const int k2 = v / C; const int c = v - k2 * C;
    const float* fw = feat_w + c * 27;
    float a2 = 0.0f;
    #pragma unroll
    for (int j = 0; j < 27; ++j) a2 = fmaf(s_g[(10 + k2) * 27 + j], fw[j], a2);
    a2 = fmaf(feat_b[c], s_rs[10 + k2], a2) + A_.std_b[I][k2];
    s_std[v] = a2;
  }
  __syncthreads();

  // ---- phase 4b: mahal — wave g handles classes {g, g+5}, all lanes ----
  {
    const int g  = t >> 6;     // 0..4
    const int ln = t & 63;
    float m0 = 0.0f, m1 = 0.0f;
    for (int c = ln; c < C; c += 64) {
      {
        const float sd  = s_std[g * C + c];
        const float eps = jax_normal_pt(fk0, fk1, (uint32_t)((b * 10 + g) * C + c));
        m0 = fmaf(sd * sd, eps * eps, m0);
      }
      {
        const float sd  = s_std[(g + 5) * C + c];
        const float eps = jax_normal_pt(fk0, fk1, (uint32_t)((b * 10 + g + 5) * C + c));
        m1 = fmaf(sd * sd, eps * eps, m1);
      }
    }
    #pragma unroll
    for (int off = 32; off > 0; off >>= 1) {
      m0 += __shfl_down(m0, off, 64);
      m1 += __shfl_down(m1, off, 64);
    }
    if (ln == 0) { s_pt[g] = m0; s_pt[g + 5] = m1; }
  }
  __syncthreads();
  if (t == 0) {
    float best = -INFINITY; int bi = 0;
    #pragma unroll
    for (int k2 = 0; k2 < 10; ++k2) {
      float m = -0.5f * s_pt[k2];
      if (m > best) { best = m; bi = k2; }
    }
    A_.scores[b * 5 + I] = best;
    *s_idx = bi;
  }
  __syncthreads();

  // ---- phase 5: outputs (mean recomputed for argmax class; std from LDS) --
  const int idx = *s_idx;
  for (int c = t; c < C; c += 320) {
    const float* fw = feat_w + c * 27;
    float a1 = 0.0f;
    #pragma unroll
    for (int j = 0; j < 27; ++j) a1 = fmaf(s_g[idx * 27 + j], fw[j], a1);
    a1 = fmaf(feat_b[c], s_rs[idx], a1) + A_.mu_b[I][idx];
    A_.mean_out[I][(size_t)b * C + c] = a1;
    A_.std_out[I][(size_t)b * C + c]  = s_std[idx * C + c];
  }
}

__global__ __launch_bounds__(320)
void ood_b(OodArgs A_) {
  __shared__ float smem[571 + 5120];   // worst case C=512
  switch (blockIdx.y) {
    case 0: stageB<0,  64>(A_, smem); break;
    case 1: stageB<1,  64>(A_, smem); break;
    case 2: stageB<2, 128>(A_, smem); break;
    case 3: stageB<3, 256>(A_, smem); break;
    default: stageB<4, 512>(A_, smem); break;
  }
}

__global__ void ood_clf(const float* __restrict__ scores,  // (B,5)
                        const float* __restrict__ clf_w,   // (1,5)
                        const float* __restrict__ clf_b,   // (1,)
                        float* __restrict__ out) {         // (B,)
  int b = blockIdx.x * blockDim.x + threadIdx.x;
  if (b < B_SZ) {
    float acc = clf_b[0];
    #pragma unroll
    for (int i = 0; i < 5; ++i) acc = fmaf(scores[b * 5 + i], clf_w[i], acc);
    out[b] = acc;
  }
}

extern "C" void kernel_launch(void* const* d_in, const int* in_sizes, int n_in,
                              void* d_out, int out_size, void* d_ws, size_t ws_size,
                              hipStream_t stream) {
  (void)in_sizes; (void)n_in; (void)out_size; (void)ws_size;
  const float* clf_w = (const float*)d_in[33];
  const float* clf_b = (const float*)d_in[34];
  float* out = (float*)d_out;
  float* ws  = (float*)d_ws;   // scores[5120] | g-blobs[5120*560]

  OodArgs A_;
  A_.x       = (const float*)d_in[0];
  A_.noise_w = (const float*)d_in[1];
  A_.noise_b = (const float*)d_in[2];
  const size_t NMEAN = 1048576;
  const size_t moff[5] = {1024, 66560, 132096, 263168, 525312};
  for (int i = 0; i < 5; ++i) {
    A_.feat_w[i]   = (const float*)d_in[3 + 6 * i];
    A_.feat_b[i]   = (const float*)d_in[4 + 6 * i];
    A_.mu_w[i]     = (const float*)d_in[5 + 6 * i];
    A_.mu_b[i]     = (const float*)d_in[6 + 6 * i];
    A_.std_w[i]    = (const float*)d_in[7 + 6 * i];
    A_.std_b[i]    = (const float*)d_in[8 + 6 * i];
    A_.mean_out[i] = out + moff[i];
    A_.std_out[i]  = out + moff[i] + NMEAN;
    tf2x32(0u, 42u, 0u, (uint32_t)i, A_.fk0[i], A_.fk1[i]);
  }
  A_.scores = ws;
  A_.gws    = ws + 5120;

  ood_a<<<dim3(B_SZ, 5), 320, 0, stream>>>(A_);
  ood_b<<<dim3(B_SZ, 5), 320, 0, stream>>>(A_);
  ood_clf<<<(B_SZ + 255) / 256, 256, 0, stream>>>(A_.scores, clf_w, clf_b, out);
}

// Round 12
// 306.866 us; speedup vs baseline: 1.8143x; 1.0507x over previous
//
#include <hip/hip_runtime.h>
#include <cstdint>

#define B_SZ 1024
#define NTHR 640

// ---------------------------------------------------------------------------
// Threefry-2x32 (20 rounds), exactly as jax._src.prng.threefry2x32.
// ---------------------------------------------------------------------------
__host__ __device__ inline void tf2x32(uint32_t k0, uint32_t k1,
                                       uint32_t x0, uint32_t x1,
                                       uint32_t& o0, uint32_t& o1) {
  uint32_t ks2 = 0x1BD11BDAu ^ k0 ^ k1;
#define TF_RND(r) { x0 += x1; x1 = (x1 << (r)) | (x1 >> (32 - (r))); x1 ^= x0; }
  x0 += k0; x1 += k1;
  TF_RND(13) TF_RND(15) TF_RND(26) TF_RND(6)
  x0 += k1; x1 += ks2 + 1u;
  TF_RND(17) TF_RND(29) TF_RND(16) TF_RND(24)
  x0 += ks2; x1 += k0 + 2u;
  TF_RND(13) TF_RND(15) TF_RND(26) TF_RND(6)
  x0 += k0; x1 += k1 + 3u;
  TF_RND(17) TF_RND(29) TF_RND(16) TF_RND(24)
  x0 += k1; x1 += ks2 + 4u;
  TF_RND(13) TF_RND(15) TF_RND(26) TF_RND(6)
  x0 += ks2; x1 += k0 + 5u;
#undef TF_RND
  o0 = x0; o1 = x1;
}

// XLA ErfInv f32 expansion, identical coefficients.
__device__ inline float erfinv_f32(float x) {
  float w = -log1pf(-x * x);
  float p;
  if (w < 5.0f) {
    w -= 2.5f;
    p = 2.81022636e-08f;
    p = fmaf(p, w, 3.43273939e-07f);
    p = fmaf(p, w, -3.5233877e-06f);
    p = fmaf(p, w, -4.39150654e-06f);
    p = fmaf(p, w, 0.00021858087f);
    p = fmaf(p, w, -0.00125372503f);
    p = fmaf(p, w, -0.00417768164f);
    p = fmaf(p, w, 0.246640727f);
    p = fmaf(p, w, 1.50140941f);
  } else {
    w = sqrtf(w) - 3.0f;
    p = -0.000200214257f;
    p = fmaf(p, w, 0.000100950558f);
    p = fmaf(p, w, 0.00134934322f);
    p = fmaf(p, w, -0.00367342844f);
    p = fmaf(p, w, 0.00573950773f);
    p = fmaf(p, w, -0.0076224613f);
    p = fmaf(p, w, 0.00943887047f);
    p = fmaf(p, w, 1.00167406f);
    p = fmaf(p, w, 2.83297682f);
  }
  return p * x;
}

__device__ inline float jax_normal_pt(uint32_t k0, uint32_t k1, uint32_t e) {
  uint32_t o0, o1;
  tf2x32(k0, k1, 0u, e, o0, o1);
  uint32_t bits = o0 ^ o1;
  float f = __uint_as_float((bits >> 9) | 0x3f800000u) - 1.0f;
  const float LO = -0.99999994f;
  float u = fmaxf(LO, fmaf(f, 2.0f, LO));
  return 1.41421356f * erfinv_f32(u);
}

struct OodArgs {
  const float* x;
  const float* noise_w;
  const float* noise_b;
  const float* feat_w[5];
  const float* feat_b[5];
  const float* mu_w[5];
  const float* mu_b[5];
  const float* std_w[5];
  const float* std_b[5];
  float* mean_out[5];
  float* std_out[5];
  float* scores;   // ws[0..5120)
  float* gws;      // ws + 5120: per (b,I) 560 floats: g[540] | rs[20]
  uint32_t fk0[5], fk1[5];
};

// Padded image buffers: 34 rows x pitch 35 per channel.  Phase-3 lane banks:
// addr = 35*ss + c -> bank 3*ss mod 32, all-distinct for ss in [0,32).
#define PITCH 35
#define CHSZ  (34 * PITCH)   // 1190
#define XSZ   (3 * CHSZ)     // 3570

// Kernel A LDS (floats)
#define A_XP   0             // 3570
#define A_XI   3570          // 3570
#define A_NW   7140          // 81
#define A_NB   7221          // 3
#define A_SMEM 7224

// ---------------------------------------------------------------------------
// KERNEL A: phases 1-3 (conv + g-reduction), g/rs blob to ws.
// 640 threads = 20 (wh,k) groups x 32 lanes, ONE output row per lane:
// per-lane live set ~40 VGPRs so the (640,8) bound pins the 64-reg bucket
// (8 waves/SIMD, 3 blocks/CU = 30 waves) WITHOUT spilling.
// ---------------------------------------------------------------------------
template<int S, int STRIDE>
__device__ __forceinline__ void stageA(const OodArgs& A_, float* smem, int i) {
  constexpr int Wd = 32 / STRIDE;

  const int b = blockIdx.x;
  const int t = threadIdx.x;

  float* s_xp = smem + A_XP;
  float* s_xi = smem + A_XI;
  float* s_nw = smem + A_NW;
  float* s_nb = smem + A_NB;

  // ---- phase 1: zero padded buffers, load x[b] interior, weights ----
  for (int p = t; p < 2 * XSZ; p += NTHR) smem[p] = 0.0f;
  if (t < 81) s_nw[t] = A_.noise_w[81 * i + t];
  if (t < 3)  s_nb[t] = A_.noise_b[3 * i + t];
  __syncthreads();
  const float* xb = A_.x + (size_t)b * 3072;
  for (int p = t; p < 3072; p += NTHR) {
    int ci = p >> 10; int rr = p & 1023; int yy = rr >> 5; int xx = rr & 31;
    s_xp[ci * CHSZ + (yy + 1) * PITCH + (xx + 1)] = xb[p];
  }
  __syncthreads();

  // ---- phase 2: xi = x + conv3x3(x, noise_w); branch-free via padding ----
  #pragma unroll
  for (int co = 0; co < 3; ++co) {
    float nwr[27];
    #pragma unroll
    for (int j = 0; j < 27; ++j) nwr[j] = s_nw[co * 27 + j];
    const float nb = s_nb[co];
    for (int p = t; p < 1024; p += NTHR) {
      const int base = (p >> 5) * PITCH + (p & 31);
      float a = nb;
      #pragma unroll
      for (int c2 = 0; c2 < 3; ++c2) {
        #pragma unroll
        for (int q = 0; q < 9; ++q)
          a = fmaf(s_xp[c2 * CHSZ + base + (q / 3) * PITCH + (q % 3)],
                   nwr[c2 * 9 + q], a);
      }
      s_xi[co * CHSZ + base + PITCH + 1] = a + s_xp[co * CHSZ + base + PITCH + 1];
    }
  }
  __syncthreads();

  // ---- phase 3: g[wh][k][ci*9+q] = sum_s w[k,s]*xi[ci,patch(s,q)] ----
  const int G  = t >> 5;          // 0..19
  const int ss = t & 31;          // row / spatial sub
  const int wh = G & 1;
  const int kk = G >> 1;
  const float* wsrc = (wh ? A_.std_w[i] : A_.mu_w[i]) + kk * S;
  float* gdst = A_.gws + (size_t)(b * 5 + i) * 560;

  if constexpr (STRIDE == 1) {
    // lane owns output row ss; padded rows ss..ss+2 at rb + u*PITCH.
    const float* wr = wsrc + ss * 32;
    const int rbase0 = ss * PITCH;
    #pragma unroll
    for (int ci = 0; ci < 3; ++ci) {
      const int rb = ci * CHSZ + rbase0;
      float acc[10];
      #pragma unroll
      for (int j = 0; j < 10; ++j) acc[j] = 0.0f;
      float Av[3], Bv[3], Cv[3];
      #pragma unroll
      for (int u = 0; u < 3; ++u) {
        Av[u] = s_xi[rb + u * PITCH + 0];
        Bv[u] = s_xi[rb + u * PITCH + 1];
      }

#define WCOMP(V, L) ((L) == 0 ? (V).x : (L) == 1 ? (V).y : (L) == 2 ? (V).z : (V).w)
#define STEP(X, P, Q, R, W0) { \
    _Pragma("unroll") \
    for (int u = 0; u < 3; ++u) R[u] = s_xi[rb + u * PITCH + (X) + 2]; \
    const float w0c = WCOMP(W0, (X) & 3); \
    _Pragma("unroll") \
    for (int dy = 0; dy < 3; ++dy) { \
      acc[dy*3+0] = fmaf(w0c, P[dy], acc[dy*3+0]); \
      acc[dy*3+1] = fmaf(w0c, Q[dy], acc[dy*3+1]); \
      acc[dy*3+2] = fmaf(w0c, R[dy], acc[dy*3+2]); \
    } \
    if (ci == 0) acc[9] += w0c; \
  }
#define G4_0(c) { const float4 w0 = *(const float4*)(wr + (c)); \
    STEP((c)+0, Av, Bv, Cv, w0) STEP((c)+1, Bv, Cv, Av, w0) \
    STEP((c)+2, Cv, Av, Bv, w0) STEP((c)+3, Av, Bv, Cv, w0) }
#define G4_1(c) { const float4 w0 = *(const float4*)(wr + (c)); \
    STEP((c)+0, Bv, Cv, Av, w0) STEP((c)+1, Cv, Av, Bv, w0) \
    STEP((c)+2, Av, Bv, Cv, w0) STEP((c)+3, Bv, Cv, Av, w0) }
#define G4_2(c) { const float4 w0 = *(const float4*)(wr + (c)); \
    STEP((c)+0, Cv, Av, Bv, w0) STEP((c)+1, Av, Bv, Cv, w0) \
    STEP((c)+2, Bv, Cv, Av, w0) STEP((c)+3, Cv, Av, Bv, w0) }

      G4_0(0) G4_1(4) G4_2(8) G4_0(12) G4_1(16) G4_2(20) G4_0(24) G4_1(28)

#undef G4_0
#undef G4_1
#undef G4_2
#undef STEP
#undef WCOMP
      // reduce across the 32 row lanes and retire this ci's acc
      #pragma unroll
      for (int j = 0; j < 10; ++j) {
        float v = acc[j];
        v += __shfl_xor(v,  1, 64);
        v += __shfl_xor(v,  2, 64);
        v += __shfl_xor(v,  4, 64);
        v += __shfl_xor(v,  8, 64);
        v += __shfl_xor(v, 16, 64);
        acc[j] = v;
      }
      if (ss == 0) {
        #pragma unroll
        for (int j = 0; j < 9; ++j)
          gdst[(wh * 10 + kk) * 27 + ci * 9 + j] = acc[j];
        if (ci == 0) gdst[540 + wh * 10 + kk] = acc[9];
      }
    }
  } else {
    constexpr int PER = (S >= 32) ? (S / 32) : 1;   // 8 / 2 / 1
    #pragma unroll
    for (int ci = 0; ci < 3; ++ci) {
      float acc[10];
      #pragma unroll
      for (int j = 0; j < 10; ++j) acc[j] = 0.0f;
      if (S >= 32 || ss < S) {
        #pragma unroll
        for (int u = 0; u < PER; ++u) {
          const int s  = (S >= 32) ? (ss * PER + u) : ss;
          const int yo = s / Wd, xo = s % Wd;
          const float wx = wsrc[s];
          #pragma unroll
          for (int dy = 0; dy < 3; ++dy) {
            const int base = ci * CHSZ + (yo * STRIDE + dy + 1) * PITCH + (xo * STRIDE + 1);
            #pragma unroll
            for (int dx = 0; dx < 3; ++dx)
              acc[dy * 3 + dx] = fmaf(wx, s_xi[base + dx], acc[dy * 3 + dx]);
          }
          if (ci == 0) acc[9] += wx;
        }
      }
      #pragma unroll
      for (int j = 0; j < 10; ++j) {
        float v = acc[j];
        v += __shfl_xor(v,  1, 64);
        v += __shfl_xor(v,  2, 64);
        v += __shfl_xor(v,  4, 64);
        v += __shfl_xor(v,  8, 64);
        v += __shfl_xor(v, 16, 64);
        acc[j] = v;
      }
      if (ss == 0) {
        #pragma unroll
        for (int j = 0; j < 9; ++j)
          gdst[(wh * 10 + kk) * 27 + ci * 9 + j] = acc[j];
        if (ci == 0) gdst[540 + wh * 10 + kk] = acc[9];
      }
    }
  }
}

__global__ __launch_bounds__(NTHR, 8)
void ood_a(OodArgs A_) {
  __shared__ float smem[A_SMEM];
  const int y = blockIdx.y;
  switch (y) {
    case 0:
    case 1: stageA<1024, 1>(A_, smem, y); break;
    case 2: stageA< 256, 2>(A_, smem, 2); break;
    case 3: stageA<  64, 4>(A_, smem, 3); break;
    default: stageA< 16, 8>(A_, smem, 4); break;
  }
}

// ---------------------------------------------------------------------------
// KERNEL B: phases 4a/4b/5 (std, mahal+RNG, argmax, outputs).
// ---------------------------------------------------------------------------
template<int I, int C>
__device__ __forceinline__ void stageB(const OodArgs& A_, float* smem) {
  const int b = blockIdx.x;
  const int t = threadIdx.x;

  float* s_g   = smem;             // 540
  float* s_rs  = smem + 540;       // 20
  float* s_std = smem + 560;       // 10*C
  float* s_pt  = smem + 560 + 10 * C;  // 10
  int*   s_idx = (int*)(smem + 570 + 10 * C);

  const float* feat_w = A_.feat_w[I];
  const float* feat_b = A_.feat_b[I];
  const uint32_t fk0 = A_.fk0[I], fk1 = A_.fk1[I];

  const float* gsrc = A_.gws + (size_t)(b * 5 + I) * 560;
  for (int p = t; p < 560; p += 320) smem[p] = gsrc[p];
  __syncthreads();

  // ---- phase 4a: s_std[k*C+c] for all classes ----
  for (int v = t; v < 10 * C; v += 320) {
    const int k2 = v / C; const int c = v - k2 * C;
    const float* fw = feat_w + c * 27;
    float a2 = 0.0f;
    #pragma unroll
    for (int j = 0; j < 27; ++j) a2 = fmaf(s_g[(10 + k2) * 27 + j], fw[j], a2);
    a2 = fmaf(feat_b[c], s_rs[10 + k2], a2) + A_.std_b[I][k2];
    s_std[v] = a2;
  }
  __syncthreads();

  // ---- phase 4b: mahal — wave g handles classes {g, g+5}, all lanes ----
  {
    const int g  = t >> 6;     // 0..4
    const int ln = t & 63;
    float m0 = 0.0f, m1 = 0.0f;
    for (int c = ln; c < C; c += 64) {
      {
        const float sd  = s_std[g * C + c];
        const float eps = jax_normal_pt(fk0, fk1, (uint32_t)((b * 10 + g) * C + c));
        m0 = fmaf(sd * sd, eps * eps, m0);
      }
      {
        const float sd  = s_std[(g + 5) * C + c];
        const float eps = jax_normal_pt(fk0, fk1, (uint32_t)((b * 10 + g + 5) * C + c));
        m1 = fmaf(sd * sd, eps * eps, m1);
      }
    }
    #pragma unroll
    for (int off = 32; off > 0; off >>= 1) {
      m0 += __shfl_down(m0, off, 64);
      m1 += __shfl_down(m1, off, 64);
    }
    if (ln == 0) { s_pt[g] = m0; s_pt[g + 5] = m1; }
  }
  __syncthreads();
  if (t == 0) {
    float best = -INFINITY; int bi = 0;
    #pragma unroll
    for (int k2 = 0; k2 < 10; ++k2) {
      float m = -0.5f * s_pt[k2];
      if (m > best) { best = m; bi = k2; }
    }
    A_.scores[b * 5 + I] = best;
    *s_idx = bi;
  }
  __syncthreads();

  // ---- phase 5: outputs (mean recomputed for argmax class; std from LDS) --
  const int idx = *s_idx;
  for (int c = t; c < C; c += 320) {
    const float* fw = feat_w + c * 27;
    float a1 = 0.0f;
    #pragma unroll
    for (int j = 0; j < 27; ++j) a1 = fmaf(s_g[idx * 27 + j], fw[j], a1);
    a1 = fmaf(feat_b[c], s_rs[idx], a1) + A_.mu_b[I][idx];
    A_.mean_out[I][(size_t)b * C + c] = a1;
    A_.std_out[I][(size_t)b * C + c]  = s_std[idx * C + c];
  }
}

__global__ __launch_bounds__(320)
void ood_b(OodArgs A_) {
  __shared__ float smem[571 + 5120];   // worst case C=512
  switch (blockIdx.y) {
    case 0: stageB<0,  64>(A_, smem); break;
    case 1: stageB<1,  64>(A_, smem); break;
    case 2: stageB<2, 128>(A_, smem); break;
    case 3: stageB<3, 256>(A_, smem); break;
    default: stageB<4, 512>(A_, smem); break;
  }
}

__global__ void ood_clf(const float* __restrict__ scores,  // (B,5)
                        const float* __restrict__ clf_w,   // (1,5)
                        const float* __restrict__ clf_b,   // (1,)
                        float* __restrict__ out) {         // (B,)
  int b = blockIdx.x * blockDim.x + threadIdx.x;
  if (b < B_SZ) {
    float acc = clf_b[0];
    #pragma unroll
    for (int i = 0; i < 5; ++i) acc = fmaf(scores[b * 5 + i], clf_w[i], acc);
    out[b] = acc;
  }
}

extern "C" void kernel_launch(void* const* d_in, const int* in_sizes, int n_in,
                              void* d_out, int out_size, void* d_ws, size_t ws_size,
                              hipStream_t stream) {
  (void)in_sizes; (void)n_in; (void)out_size; (void)ws_size;
  const float* clf_w = (const float*)d_in[33];
  const float* clf_b = (const float*)d_in[34];
  float* out = (float*)d_out;
  float* ws  = (float*)d_ws;   // scores[5120] | g-blobs[5120*560]

  OodArgs A_;
  A_.x       = (const float*)d_in[0];
  A_.noise_w = (const float*)d_in[1];
  A_.noise_b = (const float*)d_in[2];
  const size_t NMEAN = 1048576;
  const size_t moff[5] = {1024, 66560, 132096, 263168, 525312};
  for (int i = 0; i < 5; ++i) {
    A_.feat_w[i]   = (const float*)d_in[3 + 6 * i];
    A_.feat_b[i]   = (const float*)d_in[4 + 6 * i];
    A_.mu_w[i]     = (const float*)d_in[5 + 6 * i];
    A_.mu_b[i]     = (const float*)d_in[6 + 6 * i];
    A_.std_w[i]    = (const float*)d_in[7 + 6 * i];
    A_.std_b[i]    = (const float*)d_in[8 + 6 * i];
    A_.mean_out[i] = out + moff[i];
    A_.std_out[i]  = out + moff[i] + NMEAN;
    tf2x32(0u, 42u, 0u, (uint32_t)i, A_.fk0[i], A_.fk1[i]);
  }
  A_.scores = ws;
  A_.gws    = ws + 5120;

  ood_a<<<dim3(B_SZ, 5), NTHR, 0, stream>>>(A_);
  ood_b<<<dim3(B_SZ, 5), 320, 0, stream>>>(A_);
  ood_clf<<<(B_SZ + 255) / 256, 256, 0, stream>>>(A_.scores, clf_w, clf_b, out);
}